// Round 2
// baseline (367.370 us; speedup 1.0000x reference)
//
#include <hip/hip_runtime.h>

typedef unsigned short u16;
typedef unsigned int u32;

#define B_ 4
#define S_ 2048
#define D_ 1024
#define H_ 16
#define HD_ 64
#define M_ (B_ * S_)    // 8192 rows
#define QK_ (2 * D_)    // 2048 (Q|K feature stride in qk ws)

typedef __bf16 bf16x8 __attribute__((ext_vector_type(8)));
typedef float f32x4 __attribute__((ext_vector_type(4)));

#define MASKVAL (-1.0e30f)
#define RESCALE_THR 8.0f

// hardware RNE f32->bf16
static __device__ __forceinline__ u16 f2bf_hw(float f) {
    union { __bf16 b; u16 u; } v;
    v.b = (__bf16)f;
    return v.u;
}

// async global->LDS, 16B per lane. dst must be wave-uniform base; HW adds lane*16.
static __device__ __forceinline__ void gload16(const u16* g, u16* l) {
    __builtin_amdgcn_global_load_lds(
        (const __attribute__((address_space(1))) void*)g,
        (__attribute__((address_space(3))) void*)l, 16, 0, 0);
}

// ---------------- elementwise f32 -> bf16 convert (8 elems/thread) ----------
__global__ __launch_bounds__(256) void cvt_bf16(const float* __restrict__ src,
                                                u16* __restrict__ dst) {
    size_t i = ((size_t)blockIdx.x * 256 + threadIdx.x) * 8;
    float4 a = *(const float4*)(src + i);
    float4 b = *(const float4*)(src + i + 4);
    union { u16 h[8]; int4 v; } pk;
    pk.h[0] = f2bf_hw(a.x); pk.h[1] = f2bf_hw(a.y);
    pk.h[2] = f2bf_hw(a.z); pk.h[3] = f2bf_hw(a.w);
    pk.h[4] = f2bf_hw(b.x); pk.h[5] = f2bf_hw(b.y);
    pk.h[6] = f2bf_hw(b.z); pk.h[7] = f2bf_hw(b.w);
    *(int4*)(dst + i) = pk.v;
}

// ---------------- m97-structure bf16 GEMM: C[M,N] = A[M,K] * B[N,K]^T -------
// 128x128 tile, BK=64, 4 waves (2x2 of 64x64), global_load_lds staging,
// linear [128][64] LDS. EPI: 0 = bf16 C, 1 = transposed-Vt bf16, 2 = fp32 C.
template <int EPI>
__global__ __launch_bounds__(256) void gemm_bb(const u16* __restrict__ A,
                                               const u16* __restrict__ Bw,
                                               void* __restrict__ Cout,
                                               int Ndim, int Kdim) {
    __shared__ u16 Alds[128 * 64];
    __shared__ u16 Blds[128 * 64];
    const int t = threadIdx.x;
    const int bx = blockIdx.x, by = blockIdx.y;
    const int wave = t >> 6, lane = t & 63;
    const int ml = lane & 15, quad = lane >> 4;
    const int wm = (wave >> 1) * 64, wn = (wave & 1) * 64;
    const int rowA0 = by * 128, rowB0 = bx * 128;
    const int sr8 = lane >> 3;        // 0..7   staging row within 8-row slab
    const int sc8 = (lane & 7) * 8;   // 0..56  staging col (bf16 elems)

    f32x4 acc[4][4];
    const f32x4 zero = {0.f, 0.f, 0.f, 0.f};
#pragma unroll
    for (int i = 0; i < 4; ++i)
#pragma unroll
        for (int j = 0; j < 4; ++j) acc[i][j] = zero;

    for (int k0 = 0; k0 < Kdim; k0 += 64) {
        __syncthreads();
#pragma unroll
        for (int p = 0; p < 4; ++p) {
            const int rbase = wave * 32 + p * 8;   // wave-uniform slab base
            gload16(&A[(size_t)(rowA0 + rbase + sr8) * Kdim + k0 + sc8],
                    &Alds[rbase * 64]);
            gload16(&Bw[(size_t)(rowB0 + rbase + sr8) * Kdim + k0 + sc8],
                    &Blds[rbase * 64]);
        }
        __syncthreads();
#pragma unroll
        for (int kc = 0; kc < 2; ++kc) {
            bf16x8 a[4], b[4];
#pragma unroll
            for (int i = 0; i < 4; ++i)
                a[i] = *(const bf16x8*)(&Alds[(wm + i * 16 + ml) * 64 + kc * 32 + quad * 8]);
#pragma unroll
            for (int j = 0; j < 4; ++j)
                b[j] = *(const bf16x8*)(&Blds[(wn + j * 16 + ml) * 64 + kc * 32 + quad * 8]);
#pragma unroll
            for (int i = 0; i < 4; ++i)
#pragma unroll
                for (int j = 0; j < 4; ++j)
                    acc[i][j] = __builtin_amdgcn_mfma_f32_16x16x32_bf16(a[i], b[j], acc[i][j], 0, 0, 0);
        }
    }

    if constexpr (EPI == 0) {
        u16* C = (u16*)Cout;
#pragma unroll
        for (int i = 0; i < 4; ++i)
#pragma unroll
            for (int j = 0; j < 4; ++j)
#pragma unroll
                for (int r = 0; r < 4; ++r) {
                    int row = rowA0 + wm + i * 16 + quad * 4 + r;
                    int col = rowB0 + wn + j * 16 + ml;
                    C[(size_t)row * Ndim + col] = f2bf_hw(acc[i][j][r]);
                }
    } else if constexpr (EPI == 1) {
        u16* Vt = (u16*)Cout;
#pragma unroll
        for (int i = 0; i < 4; ++i)
#pragma unroll
            for (int j = 0; j < 4; ++j) {
                int row0 = rowA0 + wm + i * 16 + quad * 4;  // token, multiple of 4
                int col = rowB0 + wn + j * 16 + ml;         // V feature
                int b = row0 >> 11;
                int s0 = row0 & (S_ - 1);
                union { u16 h[4]; ushort4 v; } pk;
#pragma unroll
                for (int r = 0; r < 4; ++r) pk.h[r] = f2bf_hw(acc[i][j][r]);
                *(ushort4*)(&Vt[((size_t)(b * D_ + col)) * S_ + s0]) = pk.v;
            }
    } else {
        float* C = (float*)Cout;
#pragma unroll
        for (int i = 0; i < 4; ++i)
#pragma unroll
            for (int j = 0; j < 4; ++j)
#pragma unroll
                for (int r = 0; r < 4; ++r) {
                    int row = rowA0 + wm + i * 16 + quad * 4 + r;
                    int col = rowB0 + wn + j * 16 + ml;
                    C[(size_t)row * Ndim + col] = acc[i][j][r];
                }
    }
}

// attn2: uniform-work flash attention.
// This round: T14 async-STAGE prefetch (regs for tile t+1 in flight under
// compute of tile t), T13 defer-max (THR=8), T5 setprio around MFMA clusters.
__global__ __launch_bounds__(256, 2) void attn2(const u16* __restrict__ qk,
                                                const u16* __restrict__ Vt,
                                                u16* __restrict__ AO) {
    __shared__ u16 Klds[64][68];
    __shared__ u16 Vlds[64][68];
    __shared__ u16 Plds[4][32 * 68];
    const int t = threadIdx.x;
    const int wave = t >> 6, lane = t & 63;
    const int ml = lane & 15, quad = lane >> 4;
    const int j = blockIdx.x >> 6;       // 0..7
    const int bh = blockIdx.x & 63;      // head id
    const int b = bh >> 4, h = bh & 15;
    const size_t rowbase = (size_t)b * S_;
    const int sr = t >> 3, sseg = (t & 7) * 8;

    int qw[2], ktw[2];
    qw[0] = j * 128 + wave * 32;
    qw[1] = (15 - j) * 128 + wave * 32;
    ktw[0] = (qw[0] + 31) >> 6;
    ktw[1] = (qw[1] + 31) >> 6;
    const int ktmax = ((15 - j) * 128 + 127) >> 6;

    bf16x8 qf[2][2][2];
#pragma unroll
    for (int T = 0; T < 2; ++T)
#pragma unroll
        for (int mi = 0; mi < 2; ++mi)
#pragma unroll
            for (int kc = 0; kc < 2; ++kc)
                qf[T][mi][kc] = *(const bf16x8*)(&qk[(rowbase + qw[T] + mi * 16 + ml) * QK_ +
                                                     h * HD_ + kc * 32 + quad * 8]);

    f32x4 o[2][2][4];
    float m[2][2][4], ls[2][2][4];
    const f32x4 zero = {0.f, 0.f, 0.f, 0.f};
#pragma unroll
    for (int T = 0; T < 2; ++T)
#pragma unroll
        for (int mi = 0; mi < 2; ++mi) {
#pragma unroll
            for (int nd = 0; nd < 4; ++nd) o[T][mi][nd] = zero;
#pragma unroll
            for (int r = 0; r < 4; ++r) { m[T][mi][r] = MASKVAL; ls[T][mi][r] = 0.f; }
        }

    // T14: register prefetch of the next K/V tile
    int4 kreg[2], vreg[2];
    auto LOADT = [&](int kt) {
        const int kb = kt * 64;
#pragma unroll
        for (int p = 0; p < 2; ++p) {
            int r = sr + p * 32;
            kreg[p] = *(const int4*)(&qk[(rowbase + kb + r) * QK_ + D_ + h * HD_ + sseg]);
            vreg[p] = *(const int4*)(&Vt[(size_t)(bh * HD_ + r) * S_ + kb + sseg]);
        }
    };
    LOADT(0);

    for (int kt = 0; kt <= ktmax; ++kt) {
        __syncthreads();               // previous tile's LDS reads done
#pragma unroll
        for (int p = 0; p < 2; ++p) {
            int r = sr + p * 32;
            *(int4*)(&Klds[r][sseg]) = kreg[p];
            *(int4*)(&Vlds[r][sseg]) = vreg[p];
        }
        __syncthreads();               // LDS ready
        if (kt < ktmax) LOADT(kt + 1); // issue next-tile loads; latency hides under compute
        if (kt > ktw[1]) continue;     // idle round for this wave (barriers stay matched)

        const int kb = kt * 64;
        bf16x8 kf[4][2], vf[4][2];
#pragma unroll
        for (int ni = 0; ni < 4; ++ni)
#pragma unroll
            for (int kc = 0; kc < 2; ++kc) {
                kf[ni][kc] = *(const bf16x8*)(&Klds[ni * 16 + ml][kc * 32 + quad * 8]);
                vf[ni][kc] = *(const bf16x8*)(&Vlds[ni * 16 + ml][kc * 32 + quad * 8]);
            }

#pragma unroll
        for (int T = 0; T < 2; ++T) {
            if (kt > ktw[T]) continue;
            const int qT = qw[T];
            f32x4 sc[2][4];
            __builtin_amdgcn_s_setprio(1);
#pragma unroll
            for (int mi = 0; mi < 2; ++mi)
#pragma unroll
                for (int ni = 0; ni < 4; ++ni) {
                    f32x4 s = zero;
#pragma unroll
                    for (int kc = 0; kc < 2; ++kc)
                        s = __builtin_amdgcn_mfma_f32_16x16x32_bf16(qf[T][mi][kc], kf[ni][kc], s, 0, 0, 0);
                    sc[mi][ni] = s;
                }
            __builtin_amdgcn_s_setprio(0);
            if (kb + 63 <= qT) {       // interior tile: no masking VALU
#pragma unroll
                for (int mi = 0; mi < 2; ++mi)
#pragma unroll
                    for (int ni = 0; ni < 4; ++ni)
#pragma unroll
                        for (int r = 0; r < 4; ++r) sc[mi][ni][r] *= 0.125f;
            } else {
#pragma unroll
                for (int mi = 0; mi < 2; ++mi)
#pragma unroll
                    for (int ni = 0; ni < 4; ++ni)
#pragma unroll
                        for (int r = 0; r < 4; ++r) {
                            int q = qT + mi * 16 + quad * 4 + r;
                            int k = kb + ni * 16 + ml;
                            float v = sc[mi][ni][r] * 0.125f;
                            sc[mi][ni][r] = (k > q) ? MASKVAL : v;
                        }
            }
#pragma unroll
            for (int mi = 0; mi < 2; ++mi) {
                float tm[4];
#pragma unroll
                for (int r = 0; r < 4; ++r)
                    tm[r] = fmaxf(fmaxf(sc[mi][0][r], sc[mi][1][r]),
                                  fmaxf(sc[mi][2][r], sc[mi][3][r]));
#pragma unroll
                for (int off = 1; off <= 8; off <<= 1)
#pragma unroll
                    for (int r = 0; r < 4; ++r)
                        tm[r] = fmaxf(tm[r], __shfl_xor(tm[r], off, 64));
                // T13 defer-max: only rescale when the max actually moved by >THR
                bool need = false;
#pragma unroll
                for (int r = 0; r < 4; ++r) need |= (tm[r] > m[T][mi][r] + RESCALE_THR);
                if (__any(need)) {
                    float al[4];
#pragma unroll
                    for (int r = 0; r < 4; ++r) {
                        float mn = fmaxf(m[T][mi][r], tm[r]);
                        al[r] = __expf(m[T][mi][r] - mn);
                        m[T][mi][r] = mn;
                    }
#pragma unroll
                    for (int r = 0; r < 4; ++r) ls[T][mi][r] *= al[r];
#pragma unroll
                    for (int nd = 0; nd < 4; ++nd)
#pragma unroll
                        for (int r = 0; r < 4; ++r) o[T][mi][nd][r] *= al[r];
                }
#pragma unroll
                for (int ni = 0; ni < 4; ++ni)
#pragma unroll
                    for (int r = 0; r < 4; ++r)
                        sc[mi][ni][r] = __expf(sc[mi][ni][r] - m[T][mi][r]);
#pragma unroll
                for (int r = 0; r < 4; ++r)
                    ls[T][mi][r] += (sc[mi][0][r] + sc[mi][1][r]) + (sc[mi][2][r] + sc[mi][3][r]);
#pragma unroll
                for (int ni = 0; ni < 4; ++ni)
#pragma unroll
                    for (int r = 0; r < 4; ++r)
                        Plds[wave][(mi * 16 + quad * 4 + r) * 68 + ni * 16 + ml] = f2bf_hw(sc[mi][ni][r]);
            }
            asm volatile("s_waitcnt lgkmcnt(0)" ::: "memory");
            bf16x8 pf[2][2];
#pragma unroll
            for (int mi = 0; mi < 2; ++mi)
#pragma unroll
                for (int kc = 0; kc < 2; ++kc)
                    pf[mi][kc] = *(const bf16x8*)(&Plds[wave][(mi * 16 + ml) * 68 + kc * 32 + quad * 8]);
            __builtin_amdgcn_s_setprio(1);
#pragma unroll
            for (int mi = 0; mi < 2; ++mi)
#pragma unroll
                for (int nd = 0; nd < 4; ++nd)
#pragma unroll
                    for (int kc = 0; kc < 2; ++kc)
                        o[T][mi][nd] = __builtin_amdgcn_mfma_f32_16x16x32_bf16(pf[mi][kc], vf[nd][kc],
                                                                               o[T][mi][nd], 0, 0, 0);
            __builtin_amdgcn_s_setprio(0);
        }
    }
    // epilogue: delayed l reduction + normalize + store
#pragma unroll
    for (int T = 0; T < 2; ++T)
#pragma unroll
        for (int mi = 0; mi < 2; ++mi) {
            float s4[4], rl[4];
#pragma unroll
            for (int r = 0; r < 4; ++r) s4[r] = ls[T][mi][r];
#pragma unroll
            for (int off = 1; off <= 8; off <<= 1)
#pragma unroll
                for (int r = 0; r < 4; ++r) s4[r] += __shfl_xor(s4[r], off, 64);
#pragma unroll
            for (int r = 0; r < 4; ++r) rl[r] = 1.0f / s4[r];
#pragma unroll
            for (int nd = 0; nd < 4; ++nd)
#pragma unroll
                for (int r = 0; r < 4; ++r) {
                    int srow = qw[T] + mi * 16 + quad * 4 + r;
                    AO[(rowbase + srow) * D_ + h * HD_ + nd * 16 + ml] =
                        f2bf_hw(o[T][mi][nd][r] * rl[r]);
                }
        }
}

// 16B-per-thread d2d copy
__global__ __launch_bounds__(256) void copy16(const int4* __restrict__ src,
                                              int4* __restrict__ dst) {
    size_t i = (size_t)blockIdx.x * 256 + threadIdx.x;
    dst[i] = src[i];
}

extern "C" void kernel_launch(void* const* d_in, const int* in_sizes, int n_in,
                              void* d_out, int out_size, void* d_ws, size_t ws_size,
                              hipStream_t stream) {
    const float* x = (const float*)d_in[0];      // [B,S,D] f32
    const float* wqkv = (const float*)d_in[1];   // [3D,D] f32
    const float* wproj = (const float*)d_in[2];  // [D,D] f32
    float* out = (float*)d_out;                  // [B,S,D] fp32

    // workspace: qk [M,2D] bf16 (33.55 MB) + Vt [B*H*HD, S] bf16 (16.78 MB)
    u16* qkw = (u16*)d_ws;
    u16* Vtw = qkw + (size_t)M_ * QK_;

    // d_out doubles as bf16 scratch until the final projection:
    //   [0 , 8M)  xb (x bf16, dead after gemm_vt)  [8M,9M) wprojb  [9M,12M) wqkvb
    u16* xb = (u16*)d_out;
    u16* wprojb = xb + (size_t)M_ * D_;
    u16* wqkvb = wprojb + (size_t)D_ * D_;

    // If workspace is big enough, AO + wproj live there: copy16 disappears.
    const size_t need = ((size_t)M_ * QK_ + 8388608 /*Vt*/ + (size_t)M_ * D_ /*AO*/ +
                         (size_t)D_ * D_ /*wproj*/) * sizeof(u16);
    const bool bigws = ws_size >= need;
    u16* AOb    = bigws ? (Vtw + (size_t)8388608) : xb;
    u16* wprojd = bigws ? (AOb + (size_t)M_ * D_) : wprojb;
    u16* AOp    = bigws ? AOb : qkw;                       // proj A operand
    u16* wprojp = bigws ? wprojd : qkw + (size_t)M_ * D_;  // proj B operand

    // f32 -> bf16 converts (one-time)
    cvt_bf16<<<dim3(M_ * D_ / 2048), 256, 0, stream>>>(x, xb);
    cvt_bf16<<<dim3(D_ * D_ / 2048), 256, 0, stream>>>(wproj, wprojd);
    cvt_bf16<<<dim3(3 * D_ * D_ / 2048), 256, 0, stream>>>(wqkv, wqkvb);

    // QK projection: [M,2D] bf16
    gemm_bb<0><<<dim3(QK_ / 128, M_ / 128), 256, 0, stream>>>(xb, wqkvb, qkw, QK_, D_);
    // V projection with transposed epilogue
    gemm_bb<1><<<dim3(D_ / 128, M_ / 128), 256, 0, stream>>>(
        xb, wqkvb + (size_t)QK_ * D_, Vtw, D_, D_);
    // attention
    attn2<<<dim3(512), 256, 0, stream>>>(qkw, Vtw, AOb);
    if (!bigws) {
        // move AO + wprojb (contiguous 9M u16) out of d_out before proj writes it
        copy16<<<dim3((unsigned)(((size_t)M_ * D_ + (size_t)D_ * D_) * 2 / (256 * 16))),
                 256, 0, stream>>>((const int4*)AOb, (int4*)qkw);
    }
    // output projection: fp32 out
    gemm_bb<2><<<dim3(D_ / 128, M_ / 128), 256, 0, stream>>>(AOp, wprojp, out, D_, D_);
}

// Round 3
// 303.059 us; speedup vs baseline: 1.2122x; 1.2122x over previous
//
#include <hip/hip_runtime.h>

typedef unsigned short u16;
typedef unsigned int u32;

#define B_ 4
#define S_ 2048
#define D_ 1024
#define H_ 16
#define HD_ 64
#define M_ (B_ * S_)    // 8192 rows
#define QK_ (2 * D_)    // 2048 (Q|K feature stride in qk ws)

typedef __bf16 bf16x8 __attribute__((ext_vector_type(8)));
typedef float f32x4 __attribute__((ext_vector_type(4)));

#define MASKVAL (-1.0e30f)
#define RESCALE_THR 8.0f

// hardware RNE f32->bf16
static __device__ __forceinline__ u16 f2bf_hw(float f) {
    union { __bf16 b; u16 u; } v;
    v.b = (__bf16)f;
    return v.u;
}

// async global->LDS, 16B per lane. dst must be wave-uniform base; HW adds lane*16.
static __device__ __forceinline__ void gload16(const u16* g, u16* l) {
    __builtin_amdgcn_global_load_lds(
        (const __attribute__((address_space(1))) void*)g,
        (__attribute__((address_space(3))) void*)l, 16, 0, 0);
}

// ---------------- elementwise f32 -> bf16 convert (8 elems/thread) ----------
__global__ __launch_bounds__(256) void cvt_bf16(const float* __restrict__ src,
                                                u16* __restrict__ dst) {
    size_t i = ((size_t)blockIdx.x * 256 + threadIdx.x) * 8;
    float4 a = *(const float4*)(src + i);
    float4 b = *(const float4*)(src + i + 4);
    union { u16 h[8]; int4 v; } pk;
    pk.h[0] = f2bf_hw(a.x); pk.h[1] = f2bf_hw(a.y);
    pk.h[2] = f2bf_hw(a.z); pk.h[3] = f2bf_hw(a.w);
    pk.h[4] = f2bf_hw(b.x); pk.h[5] = f2bf_hw(b.y);
    pk.h[6] = f2bf_hw(b.z); pk.h[7] = f2bf_hw(b.w);
    *(int4*)(dst + i) = pk.v;
}

// ---------------- m97-structure bf16 GEMM: C[M,N] = A[M,K] * B[N,K]^T -------
// 128x128 tile, BK=64, 4 waves (2x2 of 64x64), global_load_lds staging,
// linear [128][64] LDS. EPI: 0 = bf16 C, 1 = transposed-Vt bf16, 2 = fp32 C.
template <int EPI>
__global__ __launch_bounds__(256) void gemm_bb(const u16* __restrict__ A,
                                               const u16* __restrict__ Bw,
                                               void* __restrict__ Cout,
                                               int Ndim, int Kdim) {
    __shared__ u16 Alds[128 * 64];
    __shared__ u16 Blds[128 * 64];
    const int t = threadIdx.x;
    const int bx = blockIdx.x, by = blockIdx.y;
    const int wave = t >> 6, lane = t & 63;
    const int ml = lane & 15, quad = lane >> 4;
    const int wm = (wave >> 1) * 64, wn = (wave & 1) * 64;
    const int rowA0 = by * 128, rowB0 = bx * 128;
    const int sr8 = lane >> 3;        // 0..7   staging row within 8-row slab
    const int sc8 = (lane & 7) * 8;   // 0..56  staging col (bf16 elems)

    f32x4 acc[4][4];
    const f32x4 zero = {0.f, 0.f, 0.f, 0.f};
#pragma unroll
    for (int i = 0; i < 4; ++i)
#pragma unroll
        for (int j = 0; j < 4; ++j) acc[i][j] = zero;

    for (int k0 = 0; k0 < Kdim; k0 += 64) {
        __syncthreads();
#pragma unroll
        for (int p = 0; p < 4; ++p) {
            const int rbase = wave * 32 + p * 8;   // wave-uniform slab base
            gload16(&A[(size_t)(rowA0 + rbase + sr8) * Kdim + k0 + sc8],
                    &Alds[rbase * 64]);
            gload16(&Bw[(size_t)(rowB0 + rbase + sr8) * Kdim + k0 + sc8],
                    &Blds[rbase * 64]);
        }
        __syncthreads();
#pragma unroll
        for (int kc = 0; kc < 2; ++kc) {
            bf16x8 a[4], b[4];
#pragma unroll
            for (int i = 0; i < 4; ++i)
                a[i] = *(const bf16x8*)(&Alds[(wm + i * 16 + ml) * 64 + kc * 32 + quad * 8]);
#pragma unroll
            for (int j = 0; j < 4; ++j)
                b[j] = *(const bf16x8*)(&Blds[(wn + j * 16 + ml) * 64 + kc * 32 + quad * 8]);
#pragma unroll
            for (int i = 0; i < 4; ++i)
#pragma unroll
                for (int j = 0; j < 4; ++j)
                    acc[i][j] = __builtin_amdgcn_mfma_f32_16x16x32_bf16(a[i], b[j], acc[i][j], 0, 0, 0);
        }
    }

    if constexpr (EPI == 0) {
        u16* C = (u16*)Cout;
#pragma unroll
        for (int i = 0; i < 4; ++i)
#pragma unroll
            for (int j = 0; j < 4; ++j)
#pragma unroll
                for (int r = 0; r < 4; ++r) {
                    int row = rowA0 + wm + i * 16 + quad * 4 + r;
                    int col = rowB0 + wn + j * 16 + ml;
                    C[(size_t)row * Ndim + col] = f2bf_hw(acc[i][j][r]);
                }
    } else if constexpr (EPI == 1) {
        u16* Vt = (u16*)Cout;
#pragma unroll
        for (int i = 0; i < 4; ++i)
#pragma unroll
            for (int j = 0; j < 4; ++j) {
                int row0 = rowA0 + wm + i * 16 + quad * 4;  // token, multiple of 4
                int col = rowB0 + wn + j * 16 + ml;         // V feature
                int b = row0 >> 11;
                int s0 = row0 & (S_ - 1);
                union { u16 h[4]; ushort4 v; } pk;
#pragma unroll
                for (int r = 0; r < 4; ++r) pk.h[r] = f2bf_hw(acc[i][j][r]);
                *(ushort4*)(&Vt[((size_t)(b * D_ + col)) * S_ + s0]) = pk.v;
            }
    } else {
        float* C = (float*)Cout;
#pragma unroll
        for (int i = 0; i < 4; ++i)
#pragma unroll
            for (int j = 0; j < 4; ++j)
#pragma unroll
                for (int r = 0; r < 4; ++r) {
                    int row = rowA0 + wm + i * 16 + quad * 4 + r;
                    int col = rowB0 + wn + j * 16 + ml;
                    C[(size_t)row * Ndim + col] = acc[i][j][r];
                }
    }
}

// attn2: uniform-work flash attention.
// This round: double-buffered K/V staged via global_load_lds (zero VGPR cost,
// counted vmcnt across raw s_barrier = true cross-tile prefetch), T2 XOR
// swizzle both-sides (pre-swizzled global source + swizzled ds_read), scale
// folded into Q fragments, T13 defer-max, T5 setprio.
__global__ __launch_bounds__(256, 2) void attn2(const u16* __restrict__ qk,
                                                const u16* __restrict__ Vt,
                                                u16* __restrict__ AO) {
    __shared__ u16 Klds[2][64 * 64];   // linear rows; chunk XOR-swizzled by row&7
    __shared__ u16 Vlds[2][64 * 64];
    __shared__ u16 Plds[4][32 * 68];
    const int t = threadIdx.x;
    const int wave = t >> 6, lane = t & 63;
    const int ml = lane & 15, quad = lane >> 4;
    const int j = blockIdx.x >> 6;       // 0..7
    const int bh = blockIdx.x & 63;      // head id
    const int b = bh >> 4, h = bh & 15;
    const size_t rowbase = (size_t)b * S_;

    // staging geometry: lane covers row (l>>3), source chunk (l&7)^(row&7)
    const int srow8 = lane >> 3;                              // 0..7
    const int schunk = ((lane & 7) ^ srow8) * 8;              // swizzled col elems

    int qw[2], ktw[2];
    qw[0] = j * 128 + wave * 32;
    qw[1] = (15 - j) * 128 + wave * 32;
    ktw[0] = (qw[0] + 31) >> 6;
    ktw[1] = (qw[1] + 31) >> 6;
    const int ktmax = ((15 - j) * 128 + 127) >> 6;

    bf16x8 qf[2][2][2];   // [tile][mi][kc]
#pragma unroll
    for (int T = 0; T < 2; ++T)
#pragma unroll
        for (int mi = 0; mi < 2; ++mi)
#pragma unroll
            for (int kc = 0; kc < 2; ++kc) {
                bf16x8 q = *(const bf16x8*)(&qk[(rowbase + qw[T] + mi * 16 + ml) * QK_ +
                                                h * HD_ + kc * 32 + quad * 8]);
#pragma unroll
                for (int e = 0; e < 8; ++e) {
                    float f = (float)q[e] * 0.125f;   // exact pow2 scale
                    q[e] = (__bf16)f;
                }
                qf[T][mi][kc] = q;
            }

    f32x4 o[2][2][4];
    float m[2][2][4], ls[2][2][4];
    const f32x4 zero = {0.f, 0.f, 0.f, 0.f};
#pragma unroll
    for (int T = 0; T < 2; ++T)
#pragma unroll
        for (int mi = 0; mi < 2; ++mi) {
#pragma unroll
            for (int nd = 0; nd < 4; ++nd) o[T][mi][nd] = zero;
#pragma unroll
            for (int r = 0; r < 4; ++r) { m[T][mi][r] = MASKVAL; ls[T][mi][r] = 0.f; }
        }

    // stage tile kt into buffer buf: 4 gload16 per wave (2 K + 2 V)
    auto STAGE = [&](int buf, int kt) {
        const int kb = kt * 64;
#pragma unroll
        for (int p = 0; p < 2; ++p) {
            const int rbase = wave * 16 + p * 8;   // wave-uniform slab base
            gload16(&qk[(rowbase + kb + rbase + srow8) * QK_ + D_ + h * HD_ + schunk],
                    &Klds[buf][rbase * 64]);
            gload16(&Vt[(size_t)(bh * HD_ + rbase + srow8) * S_ + kb + schunk],
                    &Vlds[buf][rbase * 64]);
        }
    };

    STAGE(0, 0);

    for (int kt = 0; kt <= ktmax; ++kt) {
        const int cur = kt & 1;
        if (kt < ktmax) {
            STAGE(cur ^ 1, kt + 1);                        // next tile in flight
            asm volatile("s_waitcnt vmcnt(4)" ::: "memory");  // tile kt's 4 done
        } else {
            asm volatile("s_waitcnt vmcnt(0)" ::: "memory");
        }
        __builtin_amdgcn_s_barrier();                      // buf[cur] ready

        if (kt <= ktw[1]) {
            const int kb = kt * 64;
            bf16x8 kf[4][2], vf[4][2];
#pragma unroll
            for (int ni = 0; ni < 4; ++ni)
#pragma unroll
                for (int kc = 0; kc < 2; ++kc) {
                    const int row = ni * 16 + ml;
                    const int sw = ((kc * 4 + quad) ^ (ml & 7)) * 8;
                    kf[ni][kc] = *(const bf16x8*)(&Klds[cur][row * 64 + sw]);
                    vf[ni][kc] = *(const bf16x8*)(&Vlds[cur][row * 64 + sw]);
                }

#pragma unroll
            for (int T = 0; T < 2; ++T) {
                if (kt > ktw[T]) continue;
                const int qT = qw[T];
                f32x4 sc[2][4];
                __builtin_amdgcn_s_setprio(1);
#pragma unroll
                for (int mi = 0; mi < 2; ++mi)
#pragma unroll
                    for (int ni = 0; ni < 4; ++ni) {
                        f32x4 s = zero;
#pragma unroll
                        for (int kc = 0; kc < 2; ++kc)
                            s = __builtin_amdgcn_mfma_f32_16x16x32_bf16(qf[T][mi][kc], kf[ni][kc], s, 0, 0, 0);
                        sc[mi][ni] = s;
                    }
                __builtin_amdgcn_s_setprio(0);
                if (kb + 63 > qT) {    // boundary tile: causal mask (scores pre-scaled)
#pragma unroll
                    for (int mi = 0; mi < 2; ++mi)
#pragma unroll
                        for (int ni = 0; ni < 4; ++ni)
#pragma unroll
                            for (int r = 0; r < 4; ++r) {
                                int q = qT + mi * 16 + quad * 4 + r;
                                int k = kb + ni * 16 + ml;
                                if (k > q) sc[mi][ni][r] = MASKVAL;
                            }
                }
#pragma unroll
                for (int mi = 0; mi < 2; ++mi) {
                    float tm[4];
#pragma unroll
                    for (int r = 0; r < 4; ++r)
                        tm[r] = fmaxf(fmaxf(sc[mi][0][r], sc[mi][1][r]),
                                      fmaxf(sc[mi][2][r], sc[mi][3][r]));
#pragma unroll
                    for (int off = 1; off <= 8; off <<= 1)
#pragma unroll
                        for (int r = 0; r < 4; ++r)
                            tm[r] = fmaxf(tm[r], __shfl_xor(tm[r], off, 64));
                    // T13 defer-max: rescale only when the max moved by >THR
                    bool need = false;
#pragma unroll
                    for (int r = 0; r < 4; ++r) need |= (tm[r] > m[T][mi][r] + RESCALE_THR);
                    if (__any(need)) {
                        float al[4];
#pragma unroll
                        for (int r = 0; r < 4; ++r) {
                            float mn = fmaxf(m[T][mi][r], tm[r]);
                            al[r] = __expf(m[T][mi][r] - mn);
                            m[T][mi][r] = mn;
                        }
#pragma unroll
                        for (int r = 0; r < 4; ++r) ls[T][mi][r] *= al[r];
#pragma unroll
                        for (int nd = 0; nd < 4; ++nd)
#pragma unroll
                            for (int r = 0; r < 4; ++r) o[T][mi][nd][r] *= al[r];
                    }
#pragma unroll
                    for (int ni = 0; ni < 4; ++ni)
#pragma unroll
                        for (int r = 0; r < 4; ++r)
                            sc[mi][ni][r] = __expf(sc[mi][ni][r] - m[T][mi][r]);
#pragma unroll
                    for (int r = 0; r < 4; ++r)
                        ls[T][mi][r] += (sc[mi][0][r] + sc[mi][1][r]) + (sc[mi][2][r] + sc[mi][3][r]);
#pragma unroll
                    for (int ni = 0; ni < 4; ++ni)
#pragma unroll
                        for (int r = 0; r < 4; ++r)
                            Plds[wave][(mi * 16 + quad * 4 + r) * 68 + ni * 16 + ml] =
                                f2bf_hw(sc[mi][ni][r]);
                }
                asm volatile("s_waitcnt lgkmcnt(0)" ::: "memory");
                bf16x8 pf[2][2];
#pragma unroll
                for (int mi = 0; mi < 2; ++mi)
#pragma unroll
                    for (int kc = 0; kc < 2; ++kc)
                        pf[mi][kc] = *(const bf16x8*)(&Plds[wave][(mi * 16 + ml) * 68 + kc * 32 + quad * 8]);
                __builtin_amdgcn_s_setprio(1);
#pragma unroll
                for (int mi = 0; mi < 2; ++mi)
#pragma unroll
                    for (int nd = 0; nd < 4; ++nd)
#pragma unroll
                        for (int kc = 0; kc < 2; ++kc)
                            o[T][mi][nd] = __builtin_amdgcn_mfma_f32_16x16x32_bf16(pf[mi][kc], vf[nd][kc],
                                                                                   o[T][mi][nd], 0, 0, 0);
                __builtin_amdgcn_s_setprio(0);
            }
        }
        __builtin_amdgcn_s_barrier();   // all waves done reading buf[cur]
    }

    // epilogue: delayed l reduction + normalize + store
#pragma unroll
    for (int T = 0; T < 2; ++T)
#pragma unroll
        for (int mi = 0; mi < 2; ++mi) {
            float s4[4], rl[4];
#pragma unroll
            for (int r = 0; r < 4; ++r) s4[r] = ls[T][mi][r];
#pragma unroll
            for (int off = 1; off <= 8; off <<= 1)
#pragma unroll
                for (int r = 0; r < 4; ++r) s4[r] += __shfl_xor(s4[r], off, 64);
#pragma unroll
            for (int r = 0; r < 4; ++r) rl[r] = 1.0f / s4[r];
#pragma unroll
            for (int nd = 0; nd < 4; ++nd)
#pragma unroll
                for (int r = 0; r < 4; ++r) {
                    int srow = qw[T] + mi * 16 + quad * 4 + r;
                    AO[(rowbase + srow) * D_ + h * HD_ + nd * 16 + ml] =
                        f2bf_hw(o[T][mi][nd][r] * rl[r]);
                }
        }
}

// 16B-per-thread d2d copy
__global__ __launch_bounds__(256) void copy16(const int4* __restrict__ src,
                                              int4* __restrict__ dst) {
    size_t i = (size_t)blockIdx.x * 256 + threadIdx.x;
    dst[i] = src[i];
}

extern "C" void kernel_launch(void* const* d_in, const int* in_sizes, int n_in,
                              void* d_out, int out_size, void* d_ws, size_t ws_size,
                              hipStream_t stream) {
    const float* x = (const float*)d_in[0];      // [B,S,D] f32
    const float* wqkv = (const float*)d_in[1];   // [3D,D] f32
    const float* wproj = (const float*)d_in[2];  // [D,D] f32
    float* out = (float*)d_out;                  // [B,S,D] fp32

    // workspace: qk [M,2D] bf16 (33.55 MB) + Vt [B*H*HD, S] bf16 (16.78 MB)
    u16* qkw = (u16*)d_ws;
    u16* Vtw = qkw + (size_t)M_ * QK_;

    // d_out doubles as bf16 scratch until the final projection:
    //   [0 , 8M)  xb (x bf16, dead after gemm_vt)  [8M,9M) wprojb  [9M,12M) wqkvb
    u16* xb = (u16*)d_out;
    u16* wprojb = xb + (size_t)M_ * D_;
    u16* wqkvb = wprojb + (size_t)D_ * D_;

    // If workspace is big enough, AO + wproj live there: copy16 disappears.
    const size_t need = ((size_t)M_ * QK_ + 8388608 /*Vt*/ + (size_t)M_ * D_ /*AO*/ +
                         (size_t)D_ * D_ /*wproj*/) * sizeof(u16);
    const bool bigws = ws_size >= need;
    u16* AOb    = bigws ? (Vtw + (size_t)8388608) : xb;
    u16* wprojd = bigws ? (AOb + (size_t)M_ * D_) : wprojb;
    u16* AOp    = bigws ? AOb : qkw;                       // proj A operand
    u16* wprojp = bigws ? wprojd : qkw + (size_t)M_ * D_;  // proj B operand

    // f32 -> bf16 converts (one-time)
    cvt_bf16<<<dim3(M_ * D_ / 2048), 256, 0, stream>>>(x, xb);
    cvt_bf16<<<dim3(D_ * D_ / 2048), 256, 0, stream>>>(wproj, wprojd);
    cvt_bf16<<<dim3(3 * D_ * D_ / 2048), 256, 0, stream>>>(wqkv, wqkvb);

    // QK projection: [M,2D] bf16
    gemm_bb<0><<<dim3(QK_ / 128, M_ / 128), 256, 0, stream>>>(xb, wqkvb, qkw, QK_, D_);
    // V projection with transposed epilogue
    gemm_bb<1><<<dim3(D_ / 128, M_ / 128), 256, 0, stream>>>(
        xb, wqkvb + (size_t)QK_ * D_, Vtw, D_, D_);
    // attention
    attn2<<<dim3(512), 256, 0, stream>>>(qkw, Vtw, AOb);
    if (!bigws) {
        // move AO + wprojb (contiguous 9M u16) out of d_out before proj writes it
        copy16<<<dim3((unsigned)(((size_t)M_ * D_ + (size_t)D_ * D_) * 2 / (256 * 16))),
                 256, 0, stream>>>((const int4*)AOb, (int4*)qkw);
    }
    // output projection: fp32 out
    gemm_bb<2><<<dim3(D_ / 128, M_ / 128), 256, 0, stream>>>(AOp, wprojp, out, D_, D_);
}

// Round 4
// 269.143 us; speedup vs baseline: 1.3650x; 1.1260x over previous
//
#include <hip/hip_runtime.h>

typedef unsigned short u16;
typedef unsigned int u32;

#define B_ 4
#define S_ 2048
#define D_ 1024
#define H_ 16
#define HD_ 64
#define M_ (B_ * S_)    // 8192 rows
#define QK_ (2 * D_)    // 2048 (Q|K feature stride in qk ws)

typedef __bf16 bf16x8 __attribute__((ext_vector_type(8)));
typedef float f32x4 __attribute__((ext_vector_type(4)));

#define MASKVAL (-1.0e30f)
#define RESCALE_THR 8.0f

// hardware RNE f32->bf16
static __device__ __forceinline__ u16 f2bf_hw(float f) {
    union { __bf16 b; u16 u; } v;
    v.b = (__bf16)f;
    return v.u;
}

// async global->LDS, 16B per lane. dst must be wave-uniform base; HW adds lane*16.
static __device__ __forceinline__ void gload16(const u16* g, u16* l) {
    __builtin_amdgcn_global_load_lds(
        (const __attribute__((address_space(1))) void*)g,
        (__attribute__((address_space(3))) void*)l, 16, 0, 0);
}

// ---------------- elementwise f32 -> bf16 convert (8 elems/thread) ----------
__global__ __launch_bounds__(256) void cvt_bf16(const float* __restrict__ src,
                                                u16* __restrict__ dst) {
    size_t i = ((size_t)blockIdx.x * 256 + threadIdx.x) * 8;
    float4 a = *(const float4*)(src + i);
    float4 b = *(const float4*)(src + i + 4);
    union { u16 h[8]; int4 v; } pk;
    pk.h[0] = f2bf_hw(a.x); pk.h[1] = f2bf_hw(a.y);
    pk.h[2] = f2bf_hw(a.z); pk.h[3] = f2bf_hw(a.w);
    pk.h[4] = f2bf_hw(b.x); pk.h[5] = f2bf_hw(b.y);
    pk.h[6] = f2bf_hw(b.z); pk.h[7] = f2bf_hw(b.w);
    *(int4*)(dst + i) = pk.v;
}

// ---------------- m97-structure bf16 GEMM: C[M,N] = A[M,K] * B[N,K]^T -------
// (unchanged, known-good)
template <int EPI>
__global__ __launch_bounds__(256) void gemm_bb(const u16* __restrict__ A,
                                               const u16* __restrict__ Bw,
                                               void* __restrict__ Cout,
                                               int Ndim, int Kdim) {
    __shared__ u16 Alds[128 * 64];
    __shared__ u16 Blds[128 * 64];
    const int t = threadIdx.x;
    const int bx = blockIdx.x, by = blockIdx.y;
    const int wave = t >> 6, lane = t & 63;
    const int ml = lane & 15, quad = lane >> 4;
    const int wm = (wave >> 1) * 64, wn = (wave & 1) * 64;
    const int rowA0 = by * 128, rowB0 = bx * 128;
    const int sr8 = lane >> 3;
    const int sc8 = (lane & 7) * 8;

    f32x4 acc[4][4];
    const f32x4 zero = {0.f, 0.f, 0.f, 0.f};
#pragma unroll
    for (int i = 0; i < 4; ++i)
#pragma unroll
        for (int j = 0; j < 4; ++j) acc[i][j] = zero;

    for (int k0 = 0; k0 < Kdim; k0 += 64) {
        __syncthreads();
#pragma unroll
        for (int p = 0; p < 4; ++p) {
            const int rbase = wave * 32 + p * 8;
            gload16(&A[(size_t)(rowA0 + rbase + sr8) * Kdim + k0 + sc8],
                    &Alds[rbase * 64]);
            gload16(&Bw[(size_t)(rowB0 + rbase + sr8) * Kdim + k0 + sc8],
                    &Blds[rbase * 64]);
        }
        __syncthreads();
#pragma unroll
        for (int kc = 0; kc < 2; ++kc) {
            bf16x8 a[4], b[4];
#pragma unroll
            for (int i = 0; i < 4; ++i)
                a[i] = *(const bf16x8*)(&Alds[(wm + i * 16 + ml) * 64 + kc * 32 + quad * 8]);
#pragma unroll
            for (int j = 0; j < 4; ++j)
                b[j] = *(const bf16x8*)(&Blds[(wn + j * 16 + ml) * 64 + kc * 32 + quad * 8]);
#pragma unroll
            for (int i = 0; i < 4; ++i)
#pragma unroll
                for (int j = 0; j < 4; ++j)
                    acc[i][j] = __builtin_amdgcn_mfma_f32_16x16x32_bf16(a[i], b[j], acc[i][j], 0, 0, 0);
        }
    }

    if constexpr (EPI == 0) {
        u16* C = (u16*)Cout;
#pragma unroll
        for (int i = 0; i < 4; ++i)
#pragma unroll
            for (int j = 0; j < 4; ++j)
#pragma unroll
                for (int r = 0; r < 4; ++r) {
                    int row = rowA0 + wm + i * 16 + quad * 4 + r;
                    int col = rowB0 + wn + j * 16 + ml;
                    C[(size_t)row * Ndim + col] = f2bf_hw(acc[i][j][r]);
                }
    } else if constexpr (EPI == 1) {
        u16* Vt = (u16*)Cout;
#pragma unroll
        for (int i = 0; i < 4; ++i)
#pragma unroll
            for (int j = 0; j < 4; ++j) {
                int row0 = rowA0 + wm + i * 16 + quad * 4;
                int col = rowB0 + wn + j * 16 + ml;
                int b = row0 >> 11;
                int s0 = row0 & (S_ - 1);
                union { u16 h[4]; ushort4 v; } pk;
#pragma unroll
                for (int r = 0; r < 4; ++r) pk.h[r] = f2bf_hw(acc[i][j][r]);
                *(ushort4*)(&Vt[((size_t)(b * D_ + col)) * S_ + s0]) = pk.v;
            }
    } else {
        float* C = (float*)Cout;
#pragma unroll
        for (int i = 0; i < 4; ++i)
#pragma unroll
            for (int j = 0; j < 4; ++j)
#pragma unroll
                for (int r = 0; r < 4; ++r) {
                    int row = rowA0 + wm + i * 16 + quad * 4 + r;
                    int col = rowB0 + wn + j * 16 + ml;
                    C[(size_t)row * Ndim + col] = acc[i][j][r];
                }
    }
}

// attn3: flash attention, swapped-QK^T in-ml-domain softmax.
// Grid 1024: one 128-row q-tile per block (balanced j assignment), 4 waves.
// sc = mfma(K,Q): lane holds S[k=ni*16+quad*4+r][q=ml] -> row stats per-lane
// scalar, 2-step shfl max, packed b64 P writes to compact swizzled Plds.
__global__ __launch_bounds__(256, 3) void attn3(const u16* __restrict__ qk,
                                                const u16* __restrict__ Vt,
                                                u16* __restrict__ AO) {
    __shared__ u16 Klds[2][64 * 64];   // linear rows; chunk XOR-swizzled by row&7
    __shared__ u16 Vlds[2][64 * 64];
    __shared__ u32 Pw[4][32 * 32];     // per-wave 32q x 64k bf16 as u32 words, swizzled
    const int t = threadIdx.x;
    const int wave = t >> 6, lane = t & 63;
    const int ml = lane & 15, quad = lane >> 4;

    // balanced j assignment: per blockIdx residue class (mod 4 of jj), the four
    // j values are spread by 4 -> equal total work per residence slot.
    const int jj = blockIdx.x >> 6;      // 0..15
    const int bh = blockIdx.x & 63;      // head id
    const int t4 = jj >> 2, r4 = jj & 3;
    const int j = (t4 < 2) ? (15 - 4 * t4 - r4) : (12 - 4 * t4 + r4);
    const int b = bh >> 4, h = bh & 15;
    const size_t rowbase = (size_t)b * S_;

    const int srow8 = lane >> 3;                   // 0..7
    const int schunk = ((lane & 7) ^ srow8) * 8;   // swizzled source chunk

    const int qj0 = j * 128 + wave * 32;           // this wave's 32 q-rows
    const int ktw = 2 * j + (wave >> 1);           // last k-tile this wave needs
    const int ktmax = 2 * j + 1;                   // last k-tile in block

    // Q fragments, pre-scaled by 1/sqrt(64) = 0.125 (exact pow2)
    bf16x8 qf[2][2];   // [mi][kc]
#pragma unroll
    for (int mi = 0; mi < 2; ++mi)
#pragma unroll
        for (int kc = 0; kc < 2; ++kc) {
            bf16x8 q = *(const bf16x8*)(&qk[(rowbase + qj0 + mi * 16 + ml) * QK_ +
                                            h * HD_ + kc * 32 + quad * 8]);
#pragma unroll
            for (int e = 0; e < 8; ++e) {
                float f = (float)q[e] * 0.125f;
                q[e] = (__bf16)f;
            }
            qf[mi][kc] = q;
        }

    f32x4 o[2][4];
    float m[2], ls[2];
    const f32x4 zero = {0.f, 0.f, 0.f, 0.f};
#pragma unroll
    for (int mi = 0; mi < 2; ++mi) {
#pragma unroll
        for (int nd = 0; nd < 4; ++nd) o[mi][nd] = zero;
        m[mi] = MASKVAL; ls[mi] = 0.f;
    }

    auto STAGE = [&](int buf, int kt) {
        const int kb = kt * 64;
#pragma unroll
        for (int p = 0; p < 2; ++p) {
            const int rbase = wave * 16 + p * 8;
            gload16(&qk[(rowbase + kb + rbase + srow8) * QK_ + D_ + h * HD_ + schunk],
                    &Klds[buf][rbase * 64]);
            gload16(&Vt[(size_t)(bh * HD_ + rbase + srow8) * S_ + kb + schunk],
                    &Vlds[buf][rbase * 64]);
        }
    };

    STAGE(0, 0);

    for (int kt = 0; kt <= ktmax; ++kt) {
        const int cur = kt & 1;
        if (kt < ktmax) {
            STAGE(cur ^ 1, kt + 1);
            asm volatile("s_waitcnt vmcnt(4)" ::: "memory");
        } else {
            asm volatile("s_waitcnt vmcnt(0)" ::: "memory");
        }
        __builtin_amdgcn_s_barrier();   // buf[cur] ready

        if (kt <= ktw) {
            const int kb = kt * 64;
            bf16x8 kf[4][2], vf[4][2];
#pragma unroll
            for (int ni = 0; ni < 4; ++ni)
#pragma unroll
                for (int kc = 0; kc < 2; ++kc) {
                    const int row = ni * 16 + ml;
                    const int sw = ((kc * 4 + quad) ^ (ml & 7)) * 8;
                    kf[ni][kc] = *(const bf16x8*)(&Klds[cur][row * 64 + sw]);
                    vf[ni][kc] = *(const bf16x8*)(&Vlds[cur][row * 64 + sw]);
                }

            // swapped QK^T: sc[mi][ni] value (lane,r) = S[k=kb+ni*16+quad*4+r][q=qj0+mi*16+ml]
            f32x4 sc[2][4];
            __builtin_amdgcn_s_setprio(1);
#pragma unroll
            for (int mi = 0; mi < 2; ++mi)
#pragma unroll
                for (int ni = 0; ni < 4; ++ni) {
                    f32x4 s = zero;
#pragma unroll
                    for (int kc = 0; kc < 2; ++kc)
                        s = __builtin_amdgcn_mfma_f32_16x16x32_bf16(kf[ni][kc], qf[mi][kc], s, 0, 0, 0);
                    sc[mi][ni] = s;
                }
            __builtin_amdgcn_s_setprio(0);

            if (kb + 63 > qj0) {   // boundary tile: causal mask
#pragma unroll
                for (int mi = 0; mi < 2; ++mi) {
                    const int q = qj0 + mi * 16 + ml;
#pragma unroll
                    for (int ni = 0; ni < 4; ++ni)
#pragma unroll
                        for (int r = 0; r < 4; ++r) {
                            int k = kb + ni * 16 + quad * 4 + r;
                            if (k > q) sc[mi][ni][r] = MASKVAL;
                        }
                }
            }

#pragma unroll
            for (int mi = 0; mi < 2; ++mi) {
                // row max: 15 in-thread fmax + 2 shfl steps (cross-quad)
                float tm = sc[mi][0][0];
#pragma unroll
                for (int ni = 0; ni < 4; ++ni)
#pragma unroll
                    for (int r = 0; r < 4; ++r) tm = fmaxf(tm, sc[mi][ni][r]);
                tm = fmaxf(tm, __shfl_xor(tm, 16, 64));
                tm = fmaxf(tm, __shfl_xor(tm, 32, 64));
                // T13 defer-max
                if (__any(tm > m[mi] + RESCALE_THR)) {
                    float mn = fmaxf(m[mi], tm);
                    float al = __expf(m[mi] - mn);
                    m[mi] = mn;
                    ls[mi] *= al;
                    // transport al (ml-domain) -> accumulator rows (quad*4+r)
                    float alr[4];
#pragma unroll
                    for (int r = 0; r < 4; ++r)
                        alr[r] = __shfl(al, (lane & 48) + ((lane & 48) >> 2) + r, 64);
#pragma unroll
                    for (int nd = 0; nd < 4; ++nd)
#pragma unroll
                        for (int r = 0; r < 4; ++r) o[mi][nd][r] *= alr[r];
                }
                // exp + partial row-sum (cross-quad sum deferred to epilogue)
                float sum = 0.f;
#pragma unroll
                for (int ni = 0; ni < 4; ++ni)
#pragma unroll
                    for (int r = 0; r < 4; ++r) {
                        float e = __expf(sc[mi][ni][r] - m[mi]);
                        sc[mi][ni][r] = e;
                        sum += e;
                    }
                ls[mi] += sum;
                // pack 4 k-consecutive P values -> one b64 write (bank-optimal)
#pragma unroll
                for (int ni = 0; ni < 4; ++ni) {
                    union { u16 h[4]; ushort4 v; } pk;
#pragma unroll
                    for (int r = 0; r < 4; ++r) pk.h[r] = f2bf_hw(sc[mi][ni][r]);
                    const int row = mi * 16 + ml;
                    const int word = row * 32 +
                                     (((ni * 2 + (quad >> 1)) ^ (ml & 7)) << 2) +
                                     ((quad & 1) * 2);
                    *(ushort4*)(&Pw[wave][word]) = pk.v;
                }
            }
            asm volatile("s_waitcnt lgkmcnt(0)" ::: "memory");
            // read P back as PV A-fragments: lane holds P[q=ml][k=kc*32+quad*8+e]
            bf16x8 pf[2][2];
#pragma unroll
            for (int mi = 0; mi < 2; ++mi)
#pragma unroll
                for (int kc = 0; kc < 2; ++kc) {
                    const int row = mi * 16 + ml;
                    const int word = row * 32 + ((((kc * 4 + quad)) ^ (ml & 7)) << 2);
                    pf[mi][kc] = *(const bf16x8*)(&Pw[wave][word]);
                }
            __builtin_amdgcn_s_setprio(1);
#pragma unroll
            for (int mi = 0; mi < 2; ++mi)
#pragma unroll
                for (int nd = 0; nd < 4; ++nd)
#pragma unroll
                    for (int kc = 0; kc < 2; ++kc)
                        o[mi][nd] = __builtin_amdgcn_mfma_f32_16x16x32_bf16(pf[mi][kc], vf[nd][kc],
                                                                            o[mi][nd], 0, 0, 0);
            __builtin_amdgcn_s_setprio(0);
        }
        __builtin_amdgcn_s_barrier();   // all waves done with buf[cur]
    }

    // epilogue: cross-quad l reduction (ml-domain) + transport + store
#pragma unroll
    for (int mi = 0; mi < 2; ++mi) {
        float s = ls[mi];
        s += __shfl_xor(s, 16, 64);
        s += __shfl_xor(s, 32, 64);
        float rl = 1.0f / s;
        float rlr[4];
#pragma unroll
        for (int r = 0; r < 4; ++r)
            rlr[r] = __shfl(rl, (lane & 48) + ((lane & 48) >> 2) + r, 64);
#pragma unroll
        for (int nd = 0; nd < 4; ++nd)
#pragma unroll
            for (int r = 0; r < 4; ++r) {
                int srow = qj0 + mi * 16 + quad * 4 + r;
                AO[(rowbase + srow) * D_ + h * HD_ + nd * 16 + ml] =
                    f2bf_hw(o[mi][nd][r] * rlr[r]);
            }
    }
}

// 16B-per-thread d2d copy
__global__ __launch_bounds__(256) void copy16(const int4* __restrict__ src,
                                              int4* __restrict__ dst) {
    size_t i = (size_t)blockIdx.x * 256 + threadIdx.x;
    dst[i] = src[i];
}

extern "C" void kernel_launch(void* const* d_in, const int* in_sizes, int n_in,
                              void* d_out, int out_size, void* d_ws, size_t ws_size,
                              hipStream_t stream) {
    const float* x = (const float*)d_in[0];      // [B,S,D] f32
    const float* wqkv = (const float*)d_in[1];   // [3D,D] f32
    const float* wproj = (const float*)d_in[2];  // [D,D] f32
    float* out = (float*)d_out;                  // [B,S,D] fp32

    // workspace: qk [M,2D] bf16 (33.55 MB) + Vt [B*H*HD, S] bf16 (16.78 MB)
    u16* qkw = (u16*)d_ws;
    u16* Vtw = qkw + (size_t)M_ * QK_;

    // d_out doubles as bf16 scratch until the final projection:
    //   [0 , 8M)  xb (x bf16, dead after gemm_vt)  [8M,9M) wprojb  [9M,12M) wqkvb
    u16* xb = (u16*)d_out;
    u16* wprojb = xb + (size_t)M_ * D_;
    u16* wqkvb = wprojb + (size_t)D_ * D_;

    // If workspace is big enough, AO + wproj live there: copy16 disappears.
    const size_t need = ((size_t)M_ * QK_ + 8388608 /*Vt*/ + (size_t)M_ * D_ /*AO*/ +
                         (size_t)D_ * D_ /*wproj*/) * sizeof(u16);
    const bool bigws = ws_size >= need;
    u16* AOb    = bigws ? (Vtw + (size_t)8388608) : xb;
    u16* wprojd = bigws ? (AOb + (size_t)M_ * D_) : wprojb;
    u16* AOp    = bigws ? AOb : qkw;                       // proj A operand
    u16* wprojp = bigws ? wprojd : qkw + (size_t)M_ * D_;  // proj B operand

    // f32 -> bf16 converts (one-time)
    cvt_bf16<<<dim3(M_ * D_ / 2048), 256, 0, stream>>>(x, xb);
    cvt_bf16<<<dim3(D_ * D_ / 2048), 256, 0, stream>>>(wproj, wprojd);
    cvt_bf16<<<dim3(3 * D_ * D_ / 2048), 256, 0, stream>>>(wqkv, wqkvb);

    // QK projection: [M,2D] bf16
    gemm_bb<0><<<dim3(QK_ / 128, M_ / 128), 256, 0, stream>>>(xb, wqkvb, qkw, QK_, D_);
    // V projection with transposed epilogue
    gemm_bb<1><<<dim3(D_ / 128, M_ / 128), 256, 0, stream>>>(
        xb, wqkvb + (size_t)QK_ * D_, Vtw, D_, D_);
    // attention: 1024 blocks, one q-tile each
    attn3<<<dim3(1024), 256, 0, stream>>>(qkw, Vtw, AOb);
    if (!bigws) {
        // move AO + wprojb (contiguous 9M u16) out of d_out before proj writes it
        copy16<<<dim3((unsigned)(((size_t)M_ * D_ + (size_t)D_ * D_) * 2 / (256 * 16))),
                 256, 0, stream>>>((const int4*)AOb, (int4*)qkw);
    }
    // output projection: fp32 out
    gemm_bb<2><<<dim3(D_ / 128, M_ / 128), 256, 0, stream>>>(AOp, wprojp, out, D_, D_);
}

// Round 5
// 266.652 us; speedup vs baseline: 1.3777x; 1.0093x over previous
//
#include <hip/hip_runtime.h>

typedef unsigned short u16;
typedef unsigned int u32;

#define B_ 4
#define S_ 2048
#define D_ 1024
#define H_ 16
#define HD_ 64
#define M_ (B_ * S_)    // 8192 rows
#define QK_ (2 * D_)    // 2048 (Q|K feature stride in qk ws)

typedef __bf16 bf16x8 __attribute__((ext_vector_type(8)));
typedef float f32x4 __attribute__((ext_vector_type(4)));

#define MASKVAL (-1.0e30f)
#define RESCALE_THR 8.0f

// hardware RNE f32->bf16
static __device__ __forceinline__ u16 f2bf_hw(float f) {
    union { __bf16 b; u16 u; } v;
    v.b = (__bf16)f;
    return v.u;
}

// async global->LDS, 16B per lane. dst must be wave-uniform base; HW adds lane*16.
static __device__ __forceinline__ void gload16(const u16* g, u16* l) {
    __builtin_amdgcn_global_load_lds(
        (const __attribute__((address_space(1))) void*)g,
        (__attribute__((address_space(3))) void*)l, 16, 0, 0);
}

// ---------------- elementwise f32 -> bf16 convert (8 elems/thread) ----------
__global__ __launch_bounds__(256) void cvt_bf16(const float* __restrict__ src,
                                                u16* __restrict__ dst) {
    size_t i = ((size_t)blockIdx.x * 256 + threadIdx.x) * 8;
    float4 a = *(const float4*)(src + i);
    float4 b = *(const float4*)(src + i + 4);
    union { u16 h[8]; int4 v; } pk;
    pk.h[0] = f2bf_hw(a.x); pk.h[1] = f2bf_hw(a.y);
    pk.h[2] = f2bf_hw(a.z); pk.h[3] = f2bf_hw(a.w);
    pk.h[4] = f2bf_hw(b.x); pk.h[5] = f2bf_hw(b.y);
    pk.h[6] = f2bf_hw(b.z); pk.h[7] = f2bf_hw(b.w);
    *(int4*)(dst + i) = pk.v;
}

// ---------------- m97-structure bf16 GEMM: C[M,N] = A[M,K] * B[N,K]^T -------
// 128x128 tile, BK=64, 4 waves (2x2 of 64x64), global_load_lds staging,
// linear [128][64] LDS.
// EPI: 0 = bf16 C, 1 = transposed-Vt bf16, 2 = fp32 C,
//      3 = fused qkv (bx<16 -> bf16 qk into Cout; bx>=16 -> Vt transpose into C2)
template <int EPI>
__global__ __launch_bounds__(256) void gemm_bb(const u16* __restrict__ A,
                                               const u16* __restrict__ Bw,
                                               void* __restrict__ Cout,
                                               void* __restrict__ C2,
                                               int Ndim, int Kdim) {
    __shared__ u16 Alds[128 * 64];
    __shared__ u16 Blds[128 * 64];
    const int t = threadIdx.x;
    const int bx = blockIdx.x, by = blockIdx.y;
    const int wave = t >> 6, lane = t & 63;
    const int ml = lane & 15, quad = lane >> 4;
    const int wm = (wave >> 1) * 64, wn = (wave & 1) * 64;
    const int rowA0 = by * 128, rowB0 = bx * 128;
    const int sr8 = lane >> 3;
    const int sc8 = (lane & 7) * 8;

    f32x4 acc[4][4];
    const f32x4 zero = {0.f, 0.f, 0.f, 0.f};
#pragma unroll
    for (int i = 0; i < 4; ++i)
#pragma unroll
        for (int j = 0; j < 4; ++j) acc[i][j] = zero;

    for (int k0 = 0; k0 < Kdim; k0 += 64) {
        __syncthreads();
#pragma unroll
        for (int p = 0; p < 4; ++p) {
            const int rbase = wave * 32 + p * 8;
            gload16(&A[(size_t)(rowA0 + rbase + sr8) * Kdim + k0 + sc8],
                    &Alds[rbase * 64]);
            gload16(&Bw[(size_t)(rowB0 + rbase + sr8) * Kdim + k0 + sc8],
                    &Blds[rbase * 64]);
        }
        __syncthreads();
#pragma unroll
        for (int kc = 0; kc < 2; ++kc) {
            bf16x8 a[4], b[4];
#pragma unroll
            for (int i = 0; i < 4; ++i)
                a[i] = *(const bf16x8*)(&Alds[(wm + i * 16 + ml) * 64 + kc * 32 + quad * 8]);
#pragma unroll
            for (int j = 0; j < 4; ++j)
                b[j] = *(const bf16x8*)(&Blds[(wn + j * 16 + ml) * 64 + kc * 32 + quad * 8]);
#pragma unroll
            for (int i = 0; i < 4; ++i)
#pragma unroll
                for (int j = 0; j < 4; ++j)
                    acc[i][j] = __builtin_amdgcn_mfma_f32_16x16x32_bf16(a[i], b[j], acc[i][j], 0, 0, 0);
        }
    }

    const bool doVt = (EPI == 1) || (EPI == 3 && bx >= 16);
    if ((EPI == 0) || (EPI == 3 && !doVt)) {
        u16* C = (u16*)Cout;
#pragma unroll
        for (int i = 0; i < 4; ++i)
#pragma unroll
            for (int j = 0; j < 4; ++j)
#pragma unroll
                for (int r = 0; r < 4; ++r) {
                    int row = rowA0 + wm + i * 16 + quad * 4 + r;
                    int col = rowB0 + wn + j * 16 + ml;
                    C[(size_t)row * Ndim + col] = f2bf_hw(acc[i][j][r]);
                }
    } else if (doVt) {
        u16* Vt = (EPI == 3) ? (u16*)C2 : (u16*)Cout;
        const int voff = (EPI == 3) ? 2048 : 0;
#pragma unroll
        for (int i = 0; i < 4; ++i)
#pragma unroll
            for (int j = 0; j < 4; ++j) {
                int row0 = rowA0 + wm + i * 16 + quad * 4;  // token, multiple of 4
                int col = rowB0 + wn + j * 16 + ml - voff;  // V feature
                int b = row0 >> 11;
                int s0 = row0 & (S_ - 1);
                union { u16 h[4]; ushort4 v; } pk;
#pragma unroll
                for (int r = 0; r < 4; ++r) pk.h[r] = f2bf_hw(acc[i][j][r]);
                *(ushort4*)(&Vt[((size_t)(b * D_ + col)) * S_ + s0]) = pk.v;
            }
    } else {
        float* C = (float*)Cout;
#pragma unroll
        for (int i = 0; i < 4; ++i)
#pragma unroll
            for (int j = 0; j < 4; ++j)
#pragma unroll
                for (int r = 0; r < 4; ++r) {
                    int row = rowA0 + wm + i * 16 + quad * 4 + r;
                    int col = rowB0 + wn + j * 16 + ml;
                    C[(size_t)row * Ndim + col] = acc[i][j][r];
                }
    }
}

// attn3: flash attention, swapped-QK^T, PV one-tile software lag.
// Per iter t: STAGE(t+1) -> PV(t-1) (overlaps staging wait) -> vmcnt+barrier ->
// QK(t) + softmax(t) + P-write(t) + V(t)->regs.  Pw row stride 72 u16 makes
// both P writes (b64) and P reads (b128) bank-conflict-free per 16/8-lane group.
__global__ __launch_bounds__(256, 3) void attn3(const u16* __restrict__ qk,
                                                const u16* __restrict__ Vt,
                                                u16* __restrict__ AO) {
    __shared__ u16 Klds[2][64 * 64];   // linear rows; chunk XOR-swizzled by row&7
    __shared__ u16 Vlds[2][64 * 64];
    __shared__ u16 Pw[4][32 * 72];     // per-wave 32q x 64k bf16, stride 72
    const int t = threadIdx.x;
    const int wave = t >> 6, lane = t & 63;
    const int ml = lane & 15, quad = lane >> 4;
    const int mhx = (ml & 8) >> 1;     // bank-spreading XOR term

    // balanced j assignment (equal work per residence slot)
    const int jj = blockIdx.x >> 6;      // 0..15
    const int bh = blockIdx.x & 63;      // head id
    const int t4 = jj >> 2, r4 = jj & 3;
    const int j = (t4 < 2) ? (15 - 4 * t4 - r4) : (12 - 4 * t4 + r4);
    const int b = bh >> 4, h = bh & 15;
    const size_t rowbase = (size_t)b * S_;

    const int srow8 = lane >> 3;                   // 0..7
    const int schunk = ((lane & 7) ^ srow8) * 8;   // swizzled source chunk

    const int qj0 = j * 128 + wave * 32;           // this wave's 32 q-rows
    const int ktw = 2 * j + (wave >> 1);           // last k-tile this wave needs
    const int ktmax = 2 * j + 1;                   // last k-tile in block

    u16* pwb = &Pw[wave][0];

    // Q fragments, pre-scaled by 1/sqrt(64) = 0.125 (exact pow2)
    bf16x8 qf[2][2];   // [mi][kc]
#pragma unroll
    for (int mi = 0; mi < 2; ++mi)
#pragma unroll
        for (int kc = 0; kc < 2; ++kc) {
            bf16x8 q = *(const bf16x8*)(&qk[(rowbase + qj0 + mi * 16 + ml) * QK_ +
                                            h * HD_ + kc * 32 + quad * 8]);
#pragma unroll
            for (int e = 0; e < 8; ++e) {
                float f = (float)q[e] * 0.125f;
                q[e] = (__bf16)f;
            }
            qf[mi][kc] = q;
        }

    f32x4 o[2][4];
    float m[2], ls[2];
    const f32x4 zero = {0.f, 0.f, 0.f, 0.f};
#pragma unroll
    for (int mi = 0; mi < 2; ++mi) {
#pragma unroll
        for (int nd = 0; nd < 4; ++nd) o[mi][nd] = zero;
        m[mi] = MASKVAL; ls[mi] = 0.f;
    }

    bf16x8 vf[4][2];   // V-frags of the previous tile (register-resident)

    auto STAGE = [&](int buf, int kt) {
        const int kb = kt * 64;
#pragma unroll
        for (int p = 0; p < 2; ++p) {
            const int rbase = wave * 16 + p * 8;
            gload16(&qk[(rowbase + kb + rbase + srow8) * QK_ + D_ + h * HD_ + schunk],
                    &Klds[buf][rbase * 64]);
            gload16(&Vt[(size_t)(bh * HD_ + rbase + srow8) * S_ + kb + schunk],
                    &Vlds[buf][rbase * 64]);
        }
    };

    // PV for the tile whose P sits in Pw and whose V sits in vf[]
    auto PV = [&]() {
        bf16x8 pf[2][2];
#pragma unroll
        for (int mi = 0; mi < 2; ++mi)
#pragma unroll
            for (int kc = 0; kc < 2; ++kc)
                pf[mi][kc] = *(const bf16x8*)(&pwb[(mi * 16 + ml) * 72 +
                                                   (((kc * 4 + quad) ^ mhx) << 3)]);
        __builtin_amdgcn_s_setprio(1);
#pragma unroll
        for (int mi = 0; mi < 2; ++mi)
#pragma unroll
            for (int nd = 0; nd < 4; ++nd)
#pragma unroll
                for (int kc = 0; kc < 2; ++kc)
                    o[mi][nd] = __builtin_amdgcn_mfma_f32_16x16x32_bf16(pf[mi][kc], vf[nd][kc],
                                                                        o[mi][nd], 0, 0, 0);
        __builtin_amdgcn_s_setprio(0);
    };

    STAGE(0, 0);

    for (int kt = 0; kt <= ktmax; ++kt) {
        const int cur = kt & 1;
        if (kt < ktmax) STAGE(cur ^ 1, kt + 1);   // next tile in flight

        // PV of previous tile: overlaps the staging wait below
        if (kt >= 1 && kt - 1 <= ktw) PV();

        if (kt < ktmax) {
            asm volatile("s_waitcnt vmcnt(4)" ::: "memory");  // tile kt's 4 loads done
        } else {
            asm volatile("s_waitcnt vmcnt(0)" ::: "memory");
        }
        __builtin_amdgcn_s_barrier();             // buf[cur] ready

        if (kt <= ktw) {
            const int kb = kt * 64;
            // swapped QK^T, K-frags loaded per-ni (keeps VGPR peak low)
            f32x4 sc[2][4];
            __builtin_amdgcn_s_setprio(1);
#pragma unroll
            for (int ni = 0; ni < 4; ++ni) {
                const int row = ni * 16 + ml;
                bf16x8 kfa = *(const bf16x8*)(&Klds[cur][row * 64 + ((quad ^ (ml & 7)) << 3)]);
                bf16x8 kfb = *(const bf16x8*)(&Klds[cur][row * 64 + (((4 + quad) ^ (ml & 7)) << 3)]);
#pragma unroll
                for (int mi = 0; mi < 2; ++mi) {
                    f32x4 s = __builtin_amdgcn_mfma_f32_16x16x32_bf16(kfa, qf[mi][0], zero, 0, 0, 0);
                    sc[mi][ni] = __builtin_amdgcn_mfma_f32_16x16x32_bf16(kfb, qf[mi][1], s, 0, 0, 0);
                }
            }
            __builtin_amdgcn_s_setprio(0);

            if (kb + 63 > qj0) {   // boundary tile: causal mask
#pragma unroll
                for (int mi = 0; mi < 2; ++mi) {
                    const int q = qj0 + mi * 16 + ml;
#pragma unroll
                    for (int ni = 0; ni < 4; ++ni)
#pragma unroll
                        for (int r = 0; r < 4; ++r) {
                            int k = kb + ni * 16 + quad * 4 + r;
                            if (k > q) sc[mi][ni][r] = MASKVAL;
                        }
                }
            }

#pragma unroll
            for (int mi = 0; mi < 2; ++mi) {
                // row max: in-thread fmax + 2 shfl steps
                float tm = sc[mi][0][0];
#pragma unroll
                for (int ni = 0; ni < 4; ++ni)
#pragma unroll
                    for (int r = 0; r < 4; ++r) tm = fmaxf(tm, sc[mi][ni][r]);
                tm = fmaxf(tm, __shfl_xor(tm, 16, 64));
                tm = fmaxf(tm, __shfl_xor(tm, 32, 64));
                // T13 defer-max (O already holds all PV contributions up to kt-1)
                if (__any(tm > m[mi] + RESCALE_THR)) {
                    float mn = fmaxf(m[mi], tm);
                    float al = __expf(m[mi] - mn);
                    m[mi] = mn;
                    ls[mi] *= al;
                    float alr[4];
#pragma unroll
                    for (int r = 0; r < 4; ++r)
                        alr[r] = __shfl(al, (lane & 48) + ((lane & 48) >> 2) + r, 64);
#pragma unroll
                    for (int nd = 0; nd < 4; ++nd)
#pragma unroll
                        for (int r = 0; r < 4; ++r) o[mi][nd][r] *= alr[r];
                }
                // exp + partial row-sum
                float sum = 0.f;
#pragma unroll
                for (int ni = 0; ni < 4; ++ni)
#pragma unroll
                    for (int r = 0; r < 4; ++r) {
                        float e = __expf(sc[mi][ni][r] - m[mi]);
                        sc[mi][ni][r] = e;
                        sum += e;
                    }
                ls[mi] += sum;
                // P-write: b64, stride-72 rows -> conflict-free within 16-lane groups
#pragma unroll
                for (int ni = 0; ni < 4; ++ni) {
                    union { u16 h[4]; ushort4 v; } pk;
#pragma unroll
                    for (int r = 0; r < 4; ++r) pk.h[r] = f2bf_hw(sc[mi][ni][r]);
                    const int off = (mi * 16 + ml) * 72 +
                                    ((((2 * ni + (quad >> 1)) ^ mhx)) << 3) + ((quad & 1) << 2);
                    *(ushort4*)(&pwb[off]) = pk.v;
                }
            }
            // V(kt) -> registers for next iter's PV
#pragma unroll
            for (int ni = 0; ni < 4; ++ni) {
                const int row = ni * 16 + ml;
#pragma unroll
                for (int kc = 0; kc < 2; ++kc)
                    vf[ni][kc] = *(const bf16x8*)(&Vlds[cur][row * 64 +
                                                            (((kc * 4 + quad) ^ (ml & 7)) << 3)]);
            }
        }
        asm volatile("s_waitcnt lgkmcnt(0)" ::: "memory");  // drain V reads pre-barrier
        __builtin_amdgcn_s_barrier();   // all waves done with buf[cur]
    }

    // drain: waves whose last tile == ktmax still owe PV(ktmax)
    if (ktw == ktmax) PV();

    // epilogue: cross-quad l reduction (ml-domain) + transport + store
#pragma unroll
    for (int mi = 0; mi < 2; ++mi) {
        float s = ls[mi];
        s += __shfl_xor(s, 16, 64);
        s += __shfl_xor(s, 32, 64);
        float rl = 1.0f / s;
        float rlr[4];
#pragma unroll
        for (int r = 0; r < 4; ++r)
            rlr[r] = __shfl(rl, (lane & 48) + ((lane & 48) >> 2) + r, 64);
#pragma unroll
        for (int nd = 0; nd < 4; ++nd)
#pragma unroll
            for (int r = 0; r < 4; ++r) {
                int srow = qj0 + mi * 16 + quad * 4 + r;
                AO[(rowbase + srow) * D_ + h * HD_ + nd * 16 + ml] =
                    f2bf_hw(o[mi][nd][r] * rlr[r]);
            }
    }
}

// 16B-per-thread d2d copy
__global__ __launch_bounds__(256) void copy16(const int4* __restrict__ src,
                                              int4* __restrict__ dst) {
    size_t i = (size_t)blockIdx.x * 256 + threadIdx.x;
    dst[i] = src[i];
}

extern "C" void kernel_launch(void* const* d_in, const int* in_sizes, int n_in,
                              void* d_out, int out_size, void* d_ws, size_t ws_size,
                              hipStream_t stream) {
    const float* x = (const float*)d_in[0];      // [B,S,D] f32
    const float* wqkv = (const float*)d_in[1];   // [3D,D] f32
    const float* wproj = (const float*)d_in[2];  // [D,D] f32
    float* out = (float*)d_out;                  // [B,S,D] fp32

    // workspace: qk [M,2D] bf16 (33.55 MB) + Vt [B*H*HD, S] bf16 (16.78 MB)
    u16* qkw = (u16*)d_ws;
    u16* Vtw = qkw + (size_t)M_ * QK_;

    // d_out doubles as bf16 scratch until the final projection:
    //   [0 , 8M)  xb (x bf16, dead after qkv gemm)  [8M,9M) wprojb  [9M,12M) wqkvb
    u16* xb = (u16*)d_out;
    u16* wprojb = xb + (size_t)M_ * D_;
    u16* wqkvb = wprojb + (size_t)D_ * D_;

    // If workspace is big enough, AO + wproj live there: copy16 disappears.
    const size_t need = ((size_t)M_ * QK_ + 8388608 /*Vt*/ + (size_t)M_ * D_ /*AO*/ +
                         (size_t)D_ * D_ /*wproj*/) * sizeof(u16);
    const bool bigws = ws_size >= need;
    u16* AOb    = bigws ? (Vtw + (size_t)8388608) : xb;
    u16* wprojd = bigws ? (AOb + (size_t)M_ * D_) : wprojb;
    u16* AOp    = bigws ? AOb : qkw;                       // proj A operand
    u16* wprojp = bigws ? wprojd : qkw + (size_t)M_ * D_;  // proj B operand

    // f32 -> bf16 converts (one-time)
    cvt_bf16<<<dim3(M_ * D_ / 2048), 256, 0, stream>>>(x, xb);
    cvt_bf16<<<dim3(D_ * D_ / 2048), 256, 0, stream>>>(wproj, wprojd);
    cvt_bf16<<<dim3(3 * D_ * D_ / 2048), 256, 0, stream>>>(wqkv, wqkvb);

    // fused QKV projection: bx<16 -> qk [M,2D], bx>=16 -> Vt transpose
    gemm_bb<3><<<dim3(3 * D_ / 128, M_ / 128), 256, 0, stream>>>(
        xb, wqkvb, qkw, Vtw, QK_, D_);
    // attention: 1024 blocks, one q-tile each
    attn3<<<dim3(1024), 256, 0, stream>>>(qkw, Vtw, AOb);
    if (!bigws) {
        // move AO + wprojb (contiguous 9M u16) out of d_out before proj writes it
        copy16<<<dim3((unsigned)(((size_t)M_ * D_ + (size_t)D_ * D_) * 2 / (256 * 16))),
                 256, 0, stream>>>((const int4*)AOb, (int4*)qkw);
    }
    // output projection: fp32 out
    gemm_bb<2><<<dim3(D_ / 128, M_ / 128), 256, 0, stream>>>(
        AOp, wprojp, out, nullptr, D_, D_);
}

// Round 6
// 257.091 us; speedup vs baseline: 1.4290x; 1.0372x over previous
//
#include <hip/hip_runtime.h>

typedef unsigned short u16;
typedef unsigned int u32;

#define B_ 4
#define S_ 2048
#define D_ 1024
#define H_ 16
#define HD_ 64
#define M_ (B_ * S_)    // 8192 rows
#define QK_ (2 * D_)    // 2048 (Q|K feature stride in qk ws)
#define NT_ 16          // K=1024 / BK=64

typedef __bf16 bf16x8 __attribute__((ext_vector_type(8)));
typedef float f32x4 __attribute__((ext_vector_type(4)));

#define MASKVAL (-1.0e30f)
#define RESCALE_THR 8.0f

// hardware RNE f32->bf16
static __device__ __forceinline__ u16 f2bf_hw(float f) {
    union { __bf16 b; u16 u; } v;
    v.b = (__bf16)f;
    return v.u;
}

// async global->LDS, 16B per lane. dst must be wave-uniform base; HW adds lane*16.
static __device__ __forceinline__ void gload16(const u16* g, u16* l) {
    __builtin_amdgcn_global_load_lds(
        (const __attribute__((address_space(1))) void*)g,
        (__attribute__((address_space(3))) void*)l, 16, 0, 0);
}

// ---------------- elementwise f32 -> bf16 convert (8 elems/thread) ----------
__global__ __launch_bounds__(256) void cvt_bf16(const float* __restrict__ src,
                                                u16* __restrict__ dst) {
    size_t i = ((size_t)blockIdx.x * 256 + threadIdx.x) * 8;
    float4 a = *(const float4*)(src + i);
    float4 b = *(const float4*)(src + i + 4);
    union { u16 h[8]; int4 v; } pk;
    pk.h[0] = f2bf_hw(a.x); pk.h[1] = f2bf_hw(a.y);
    pk.h[2] = f2bf_hw(a.z); pk.h[3] = f2bf_hw(a.w);
    pk.h[4] = f2bf_hw(b.x); pk.h[5] = f2bf_hw(b.y);
    pk.h[6] = f2bf_hw(b.z); pk.h[7] = f2bf_hw(b.w);
    *(int4*)(dst + i) = pk.v;
}

// ---------------- deep-pipelined bf16 GEMM (counted-vmcnt schedule) ---------
// C[M,N] = A[M,1024] * B[N,1024]^T. BM=256, BN=128, BK=64, 512 threads,
// 8 waves = 4x2 grid of 64x64 outputs. K-tile = two col-half panels (kc=0/1),
// each staged separately via global_load_lds with pre-swizzled source.
// Per K-tile: 2 phases of {8 ds_read_b128, 3 gload16, s_barrier, lgkmcnt(0),
// setprio, 16 MFMA, barrier}; vmcnt(3) once per K-tile (never 0 mid-loop).
// EPI: 2 = fp32 C; 3 = fused qkv (bx<16 -> bf16 qk; bx>=16 -> transposed Vt).
template <int EPI>
__global__ __launch_bounds__(512, 2) void gemm8p(const u16* __restrict__ A,
                                                 const u16* __restrict__ Bw,
                                                 void* __restrict__ Cout,
                                                 void* __restrict__ C2,
                                                 int Ndim) {
    __shared__ u16 As[2][2][256 * 32];   // [buf][kc] col-half panels, 64 KB
    __shared__ u16 Bs[2][2][128 * 32];   // 32 KB
    const int t = threadIdx.x;
    const int wave = t >> 6, lane = t & 63;
    const int ml = lane & 15, quad = lane >> 4;
    const int wr = wave >> 1, wc = wave & 1;     // 4x2 waves -> 64x64 out each
    const int bx = blockIdx.x, by = blockIdx.y;
    const int rowA0 = by * 256, rowB0 = bx * 128;
    const int sr = lane >> 2;                              // 0..15 row in slab
    const int sch = ((lane & 3) ^ ((lane >> 3) & 3)) * 8;  // pre-swizzled chunk

    f32x4 acc[4][4];
    const f32x4 zero = {0.f, 0.f, 0.f, 0.f};
#pragma unroll
    for (int i = 0; i < 4; ++i)
#pragma unroll
        for (int j = 0; j < 4; ++j) acc[i][j] = zero;

    // stage one A col-half (256x32): 2 gload16/wave (= 2 vmcnt items)
    auto STAGE_A = [&](int buf, int kt, int kc) {
#pragma unroll
        for (int p = 0; p < 2; ++p) {
            const int rb = wave * 32 + p * 16;
            gload16(&A[(size_t)(rowA0 + rb + sr) * 1024 + kt * 64 + kc * 32 + sch],
                    &As[buf][kc][rb * 32]);
        }
    };
    // stage one B col-half (128x32): 1 gload16/wave
    auto STAGE_B = [&](int buf, int kt, int kc) {
        const int rb = wave * 16;
        gload16(&Bw[(size_t)(rowB0 + rb + sr) * 1024 + kt * 64 + kc * 32 + sch],
                &Bs[buf][kc][rb * 32]);
    };
    // fragment reads: chunk XOR ((row>>1)&3) -> 2-way bank aliasing (free)
    auto LDA = [&](int buf, int kc, int i) -> bf16x8 {
        const int row = wr * 64 + i * 16 + ml;
        return *(const bf16x8*)(&As[buf][kc][row * 32 + ((quad ^ ((row >> 1) & 3)) << 3)]);
    };
    auto LDB = [&](int buf, int kc, int j) -> bf16x8 {
        const int row = wc * 64 + j * 16 + ml;
        return *(const bf16x8*)(&Bs[buf][kc][row * 32 + ((quad ^ ((row >> 1) & 3)) << 3)]);
    };

    // prologue: t0 fully (6 items) + t1.kc0 (3 items); vmcnt(3) lands t0
    STAGE_A(0, 0, 0); STAGE_B(0, 0, 0);
    STAGE_A(0, 0, 1); STAGE_B(0, 0, 1);
    STAGE_A(1, 1, 0); STAGE_B(1, 1, 0);
    asm volatile("s_waitcnt vmcnt(3)" ::: "memory");
    __builtin_amdgcn_s_barrier();

    for (int kt = 0; kt < NT_; ++kt) {
        const int cur = kt & 1;
        // ---- phase 1: kc=0 compute, stage (kt+1).kc1 into other buffer
        {
            bf16x8 a[4], b[4];
#pragma unroll
            for (int i = 0; i < 4; ++i) a[i] = LDA(cur, 0, i);
#pragma unroll
            for (int j = 0; j < 4; ++j) b[j] = LDB(cur, 0, j);
            if (kt + 1 < NT_) { STAGE_A(cur ^ 1, kt + 1, 1); STAGE_B(cur ^ 1, kt + 1, 1); }
            __builtin_amdgcn_s_barrier();
            asm volatile("s_waitcnt lgkmcnt(0)" ::: "memory");
            __builtin_amdgcn_sched_barrier(0);
            __builtin_amdgcn_s_setprio(1);
#pragma unroll
            for (int i = 0; i < 4; ++i)
#pragma unroll
                for (int j = 0; j < 4; ++j)
                    acc[i][j] = __builtin_amdgcn_mfma_f32_16x16x32_bf16(a[i], b[j], acc[i][j], 0, 0, 0);
            __builtin_amdgcn_s_setprio(0);
            __builtin_amdgcn_s_barrier();
        }
        // ---- phase 2: kc=1 compute, stage (kt+2).kc0 into current buffer
        {
            bf16x8 a[4], b[4];
#pragma unroll
            for (int i = 0; i < 4; ++i) a[i] = LDA(cur, 1, i);
#pragma unroll
            for (int j = 0; j < 4; ++j) b[j] = LDB(cur, 1, j);
            if (kt + 2 < NT_) { STAGE_A(cur, kt + 2, 0); STAGE_B(cur, kt + 2, 0); }
            __builtin_amdgcn_s_barrier();
            asm volatile("s_waitcnt lgkmcnt(0)" ::: "memory");
            __builtin_amdgcn_sched_barrier(0);
            __builtin_amdgcn_s_setprio(1);
#pragma unroll
            for (int i = 0; i < 4; ++i)
#pragma unroll
                for (int j = 0; j < 4; ++j)
                    acc[i][j] = __builtin_amdgcn_mfma_f32_16x16x32_bf16(a[i], b[j], acc[i][j], 0, 0, 0);
            __builtin_amdgcn_s_setprio(0);
            // counted wait: lands (kt+1) fully; keeps (kt+2).kc0 in flight
            if (kt + 2 < NT_) { asm volatile("s_waitcnt vmcnt(3)" ::: "memory"); }
            else              { asm volatile("s_waitcnt vmcnt(0)" ::: "memory"); }
            __builtin_amdgcn_s_barrier();
        }
    }

    // epilogue
    if constexpr (EPI == 2) {
        float* C = (float*)Cout;
#pragma unroll
        for (int i = 0; i < 4; ++i)
#pragma unroll
            for (int j = 0; j < 4; ++j)
#pragma unroll
                for (int r = 0; r < 4; ++r) {
                    int row = rowA0 + wr * 64 + i * 16 + quad * 4 + r;
                    int col = rowB0 + wc * 64 + j * 16 + ml;
                    C[(size_t)row * Ndim + col] = acc[i][j][r];
                }
    } else {
        if (bx < 16) {   // qk region, bf16
            u16* C = (u16*)Cout;
#pragma unroll
            for (int i = 0; i < 4; ++i)
#pragma unroll
                for (int j = 0; j < 4; ++j)
#pragma unroll
                    for (int r = 0; r < 4; ++r) {
                        int row = rowA0 + wr * 64 + i * 16 + quad * 4 + r;
                        int col = rowB0 + wc * 64 + j * 16 + ml;
                        C[(size_t)row * Ndim + col] = f2bf_hw(acc[i][j][r]);
                    }
        } else {         // V region -> transposed Vt
            u16* Vt = (u16*)C2;
#pragma unroll
            for (int i = 0; i < 4; ++i)
#pragma unroll
                for (int j = 0; j < 4; ++j) {
                    int row0 = rowA0 + wr * 64 + i * 16 + quad * 4;  // token, mult of 4
                    int col = rowB0 + wc * 64 + j * 16 + ml - 2048;  // V feature
                    int b = row0 >> 11;
                    int s0 = row0 & (S_ - 1);
                    union { u16 h[4]; ushort4 v; } pk;
#pragma unroll
                    for (int r = 0; r < 4; ++r) pk.h[r] = f2bf_hw(acc[i][j][r]);
                    *(ushort4*)(&Vt[((size_t)(b * D_ + col)) * S_ + s0]) = pk.v;
                }
        }
    }
}

// attn3: flash attention, swapped-QK^T, PV one-tile software lag. (unchanged)
__global__ __launch_bounds__(256, 3) void attn3(const u16* __restrict__ qk,
                                                const u16* __restrict__ Vt,
                                                u16* __restrict__ AO) {
    __shared__ u16 Klds[2][64 * 64];   // linear rows; chunk XOR-swizzled by row&7
    __shared__ u16 Vlds[2][64 * 64];
    __shared__ u16 Pw[4][32 * 72];     // per-wave 32q x 64k bf16, stride 72
    const int t = threadIdx.x;
    const int wave = t >> 6, lane = t & 63;
    const int ml = lane & 15, quad = lane >> 4;
    const int mhx = (ml & 8) >> 1;     // bank-spreading XOR term

    const int jj = blockIdx.x >> 6;      // 0..15
    const int bh = blockIdx.x & 63;      // head id
    const int t4 = jj >> 2, r4 = jj & 3;
    const int j = (t4 < 2) ? (15 - 4 * t4 - r4) : (12 - 4 * t4 + r4);
    const int b = bh >> 4, h = bh & 15;
    const size_t rowbase = (size_t)b * S_;

    const int srow8 = lane >> 3;                   // 0..7
    const int schunk = ((lane & 7) ^ srow8) * 8;   // swizzled source chunk

    const int qj0 = j * 128 + wave * 32;           // this wave's 32 q-rows
    const int ktw = 2 * j + (wave >> 1);           // last k-tile this wave needs
    const int ktmax = 2 * j + 1;                   // last k-tile in block

    u16* pwb = &Pw[wave][0];

    bf16x8 qf[2][2];   // [mi][kc], pre-scaled by 0.125
#pragma unroll
    for (int mi = 0; mi < 2; ++mi)
#pragma unroll
        for (int kc = 0; kc < 2; ++kc) {
            bf16x8 q = *(const bf16x8*)(&qk[(rowbase + qj0 + mi * 16 + ml) * QK_ +
                                            h * HD_ + kc * 32 + quad * 8]);
#pragma unroll
            for (int e = 0; e < 8; ++e) {
                float f = (float)q[e] * 0.125f;
                q[e] = (__bf16)f;
            }
            qf[mi][kc] = q;
        }

    f32x4 o[2][4];
    float m[2], ls[2];
    const f32x4 zero = {0.f, 0.f, 0.f, 0.f};
#pragma unroll
    for (int mi = 0; mi < 2; ++mi) {
#pragma unroll
        for (int nd = 0; nd < 4; ++nd) o[mi][nd] = zero;
        m[mi] = MASKVAL; ls[mi] = 0.f;
    }

    bf16x8 vf[4][2];   // V-frags of the previous tile

    auto STAGE = [&](int buf, int kt) {
        const int kb = kt * 64;
#pragma unroll
        for (int p = 0; p < 2; ++p) {
            const int rbase = wave * 16 + p * 8;
            gload16(&qk[(rowbase + kb + rbase + srow8) * QK_ + D_ + h * HD_ + schunk],
                    &Klds[buf][rbase * 64]);
            gload16(&Vt[(size_t)(bh * HD_ + rbase + srow8) * S_ + kb + schunk],
                    &Vlds[buf][rbase * 64]);
        }
    };

    auto PV = [&]() {
        bf16x8 pf[2][2];
#pragma unroll
        for (int mi = 0; mi < 2; ++mi)
#pragma unroll
            for (int kc = 0; kc < 2; ++kc)
                pf[mi][kc] = *(const bf16x8*)(&pwb[(mi * 16 + ml) * 72 +
                                                   (((kc * 4 + quad) ^ mhx) << 3)]);
        __builtin_amdgcn_s_setprio(1);
#pragma unroll
        for (int mi = 0; mi < 2; ++mi)
#pragma unroll
            for (int nd = 0; nd < 4; ++nd)
#pragma unroll
                for (int kc = 0; kc < 2; ++kc)
                    o[mi][nd] = __builtin_amdgcn_mfma_f32_16x16x32_bf16(pf[mi][kc], vf[nd][kc],
                                                                        o[mi][nd], 0, 0, 0);
        __builtin_amdgcn_s_setprio(0);
    };

    STAGE(0, 0);

    for (int kt = 0; kt <= ktmax; ++kt) {
        const int cur = kt & 1;
        if (kt < ktmax) STAGE(cur ^ 1, kt + 1);

        if (kt >= 1 && kt - 1 <= ktw) PV();

        if (kt < ktmax) {
            asm volatile("s_waitcnt vmcnt(4)" ::: "memory");
        } else {
            asm volatile("s_waitcnt vmcnt(0)" ::: "memory");
        }
        __builtin_amdgcn_s_barrier();

        if (kt <= ktw) {
            const int kb = kt * 64;
            f32x4 sc[2][4];
            __builtin_amdgcn_s_setprio(1);
#pragma unroll
            for (int ni = 0; ni < 4; ++ni) {
                const int row = ni * 16 + ml;
                bf16x8 kfa = *(const bf16x8*)(&Klds[cur][row * 64 + ((quad ^ (ml & 7)) << 3)]);
                bf16x8 kfb = *(const bf16x8*)(&Klds[cur][row * 64 + (((4 + quad) ^ (ml & 7)) << 3)]);
#pragma unroll
                for (int mi = 0; mi < 2; ++mi) {
                    f32x4 s = __builtin_amdgcn_mfma_f32_16x16x32_bf16(kfa, qf[mi][0], zero, 0, 0, 0);
                    sc[mi][ni] = __builtin_amdgcn_mfma_f32_16x16x32_bf16(kfb, qf[mi][1], s, 0, 0, 0);
                }
            }
            __builtin_amdgcn_s_setprio(0);

            if (kb + 63 > qj0) {
#pragma unroll
                for (int mi = 0; mi < 2; ++mi) {
                    const int q = qj0 + mi * 16 + ml;
#pragma unroll
                    for (int ni = 0; ni < 4; ++ni)
#pragma unroll
                        for (int r = 0; r < 4; ++r) {
                            int k = kb + ni * 16 + quad * 4 + r;
                            if (k > q) sc[mi][ni][r] = MASKVAL;
                        }
                }
            }

#pragma unroll
            for (int mi = 0; mi < 2; ++mi) {
                float tm = sc[mi][0][0];
#pragma unroll
                for (int ni = 0; ni < 4; ++ni)
#pragma unroll
                    for (int r = 0; r < 4; ++r) tm = fmaxf(tm, sc[mi][ni][r]);
                tm = fmaxf(tm, __shfl_xor(tm, 16, 64));
                tm = fmaxf(tm, __shfl_xor(tm, 32, 64));
                if (__any(tm > m[mi] + RESCALE_THR)) {
                    float mn = fmaxf(m[mi], tm);
                    float al = __expf(m[mi] - mn);
                    m[mi] = mn;
                    ls[mi] *= al;
                    float alr[4];
#pragma unroll
                    for (int r = 0; r < 4; ++r)
                        alr[r] = __shfl(al, (lane & 48) + ((lane & 48) >> 2) + r, 64);
#pragma unroll
                    for (int nd = 0; nd < 4; ++nd)
#pragma unroll
                        for (int r = 0; r < 4; ++r) o[mi][nd][r] *= alr[r];
                }
                float sum = 0.f;
#pragma unroll
                for (int ni = 0; ni < 4; ++ni)
#pragma unroll
                    for (int r = 0; r < 4; ++r) {
                        float e = __expf(sc[mi][ni][r] - m[mi]);
                        sc[mi][ni][r] = e;
                        sum += e;
                    }
                ls[mi] += sum;
#pragma unroll
                for (int ni = 0; ni < 4; ++ni) {
                    union { u16 h[4]; ushort4 v; } pk;
#pragma unroll
                    for (int r = 0; r < 4; ++r) pk.h[r] = f2bf_hw(sc[mi][ni][r]);
                    const int off = (mi * 16 + ml) * 72 +
                                    ((((2 * ni + (quad >> 1)) ^ mhx)) << 3) + ((quad & 1) << 2);
                    *(ushort4*)(&pwb[off]) = pk.v;
                }
            }
#pragma unroll
            for (int ni = 0; ni < 4; ++ni) {
                const int row = ni * 16 + ml;
#pragma unroll
                for (int kc = 0; kc < 2; ++kc)
                    vf[ni][kc] = *(const bf16x8*)(&Vlds[cur][row * 64 +
                                                            (((kc * 4 + quad) ^ (ml & 7)) << 3)]);
            }
        }
        asm volatile("s_waitcnt lgkmcnt(0)" ::: "memory");
        __builtin_amdgcn_s_barrier();
    }

    if (ktw == ktmax) PV();

#pragma unroll
    for (int mi = 0; mi < 2; ++mi) {
        float s = ls[mi];
        s += __shfl_xor(s, 16, 64);
        s += __shfl_xor(s, 32, 64);
        float rl = 1.0f / s;
        float rlr[4];
#pragma unroll
        for (int r = 0; r < 4; ++r)
            rlr[r] = __shfl(rl, (lane & 48) + ((lane & 48) >> 2) + r, 64);
#pragma unroll
        for (int nd = 0; nd < 4; ++nd)
#pragma unroll
            for (int r = 0; r < 4; ++r) {
                int srow = qj0 + mi * 16 + quad * 4 + r;
                AO[(rowbase + srow) * D_ + h * HD_ + nd * 16 + ml] =
                    f2bf_hw(o[mi][nd][r] * rlr[r]);
            }
    }
}

// 16B-per-thread d2d copy
__global__ __launch_bounds__(256) void copy16(const int4* __restrict__ src,
                                              int4* __restrict__ dst) {
    size_t i = (size_t)blockIdx.x * 256 + threadIdx.x;
    dst[i] = src[i];
}

extern "C" void kernel_launch(void* const* d_in, const int* in_sizes, int n_in,
                              void* d_out, int out_size, void* d_ws, size_t ws_size,
                              hipStream_t stream) {
    const float* x = (const float*)d_in[0];      // [B,S,D] f32
    const float* wqkv = (const float*)d_in[1];   // [3D,D] f32
    const float* wproj = (const float*)d_in[2];  // [D,D] f32
    float* out = (float*)d_out;                  // [B,S,D] fp32

    // workspace: qk [M,2D] bf16 (33.55 MB) + Vt [B*H*HD, S] bf16 (16.78 MB)
    u16* qkw = (u16*)d_ws;
    u16* Vtw = qkw + (size_t)M_ * QK_;

    // d_out doubles as bf16 scratch until the final projection:
    //   [0 , 8M)  xb (x bf16, dead after qkv gemm)  [8M,9M) wprojb  [9M,12M) wqkvb
    u16* xb = (u16*)d_out;
    u16* wprojb = xb + (size_t)M_ * D_;
    u16* wqkvb = wprojb + (size_t)D_ * D_;

    // If workspace is big enough, AO + wproj live there: copy16 disappears.
    const size_t need = ((size_t)M_ * QK_ + 8388608 /*Vt*/ + (size_t)M_ * D_ /*AO*/ +
                         (size_t)D_ * D_ /*wproj*/) * sizeof(u16);
    const bool bigws = ws_size >= need;
    u16* AOb    = bigws ? (Vtw + (size_t)8388608) : xb;
    u16* wprojd = bigws ? (AOb + (size_t)M_ * D_) : wprojb;
    u16* AOp    = bigws ? AOb : qkw;                       // proj A operand
    u16* wprojp = bigws ? wprojd : qkw + (size_t)M_ * D_;  // proj B operand

    // f32 -> bf16 converts (one-time)
    cvt_bf16<<<dim3(M_ * D_ / 2048), 256, 0, stream>>>(x, xb);
    cvt_bf16<<<dim3(D_ * D_ / 2048), 256, 0, stream>>>(wproj, wprojd);
    cvt_bf16<<<dim3(3 * D_ * D_ / 2048), 256, 0, stream>>>(wqkv, wqkvb);

    // fused QKV projection (deep-pipelined): bx<16 -> qk, bx>=16 -> Vt transpose
    gemm8p<3><<<dim3(3 * D_ / 128, M_ / 256), 512, 0, stream>>>(
        xb, wqkvb, qkw, Vtw, QK_);
    // attention: 1024 blocks, one q-tile each
    attn3<<<dim3(1024), 256, 0, stream>>>(qkw, Vtw, AOb);
    if (!bigws) {
        // move AO + wprojb (contiguous 9M u16) out of d_out before proj writes it
        copy16<<<dim3((unsigned)(((size_t)M_ * D_ + (size_t)D_ * D_) * 2 / (256 * 16))),
                 256, 0, stream>>>((const int4*)AOb, (int4*)qkw);
    }
    // output projection (deep-pipelined): fp32 out
    gemm8p<2><<<dim3(D_ / 128, M_ / 256), 512, 0, stream>>>(
        AOp, wprojp, out, nullptr, D_);
}

// Round 7
// 244.912 us; speedup vs baseline: 1.5000x; 1.0497x over previous
//
#include <hip/hip_runtime.h>

typedef unsigned short u16;
typedef unsigned int u32;

#define B_ 4
#define S_ 2048
#define D_ 1024
#define H_ 16
#define HD_ 64
#define M_ (B_ * S_)    // 8192 rows
#define QK_ (2 * D_)    // 2048 (Q|K feature stride in qk ws)
#define NP_ 32          // panels: K=1024 / 32-col halves

typedef __bf16 bf16x8 __attribute__((ext_vector_type(8)));
typedef float f32x4 __attribute__((ext_vector_type(4)));

#define MASKVAL (-1.0e30f)
#define RESCALE_THR 8.0f

// hardware RNE f32->bf16
static __device__ __forceinline__ u16 f2bf_hw(float f) {
    union { __bf16 b; u16 u; } v;
    v.b = (__bf16)f;
    return v.u;
}

// async global->LDS, 16B per lane. dst must be wave-uniform base; HW adds lane*16.
static __device__ __forceinline__ void gload16(const u16* g, u16* l) {
    __builtin_amdgcn_global_load_lds(
        (const __attribute__((address_space(1))) void*)g,
        (__attribute__((address_space(3))) void*)l, 16, 0, 0);
}

// ---------------- elementwise f32 -> bf16 convert (8 elems/thread) ----------
__global__ __launch_bounds__(256) void cvt_bf16(const float* __restrict__ src,
                                                u16* __restrict__ dst) {
    size_t i = ((size_t)blockIdx.x * 256 + threadIdx.x) * 8;
    float4 a = *(const float4*)(src + i);
    float4 b = *(const float4*)(src + i + 4);
    union { u16 h[8]; int4 v; } pk;
    pk.h[0] = f2bf_hw(a.x); pk.h[1] = f2bf_hw(a.y);
    pk.h[2] = f2bf_hw(a.z); pk.h[3] = f2bf_hw(a.w);
    pk.h[4] = f2bf_hw(b.x); pk.h[5] = f2bf_hw(b.y);
    pk.h[6] = f2bf_hw(b.z); pk.h[7] = f2bf_hw(b.w);
    *(int4*)(dst + i) = pk.v;
}

// ---------------- deep-pipelined bf16 GEMM, 3-slot circular col-half LDS ----
// C[M,N] = A[M,1024] * B[N,1024]^T.  BM x 128 tile, 32-col half-panels.
// TPB/64 waves as (BM/64) x 2 grid of 64x64 outputs.  LDS = 3 slots of
// (BM+128)x32 bf16 -> 72 KB (BM=256) / 48 KB (BM=128) => 2+ blocks/CU.
// Phase p: ds_read slot p%3 | stage panel p+2 -> slot (p+2)%3 | barrier |
// lgkmcnt(0) | 16 MFMA | vmcnt(L) (panel p+1 landed, p+2 stays in flight) |
// barrier (publishes panel p+1).  Never vmcnt(0) mid-loop.
// EPI: 2 = fp32 C; 3 = fused qkv (bx<16 -> bf16 qk; bx>=16 -> transposed Vt).
template <int EPI, int BM, int TPB>
__global__ __launch_bounds__(TPB, (TPB == 512) ? 4 : 2)
void gemm8p(const u16* __restrict__ A, const u16* __restrict__ Bw,
            void* __restrict__ Cout, void* __restrict__ C2, int Ndim) {
    __shared__ u16 As[3][BM * 32];
    __shared__ u16 Bs[3][128 * 32];
    constexpr int LA = (BM * 4) / TPB;   // lane-loads per thread, A panel (=2)
    constexpr int LB = 512 / TPB;        // B panel (1 or 2)
    constexpr int L = LA + LB;           // loads per panel per wave-lane (3 or 4)
    const int t = threadIdx.x;
    const int wave = t >> 6, lane = t & 63;
    const int ml = lane & 15, quad = lane >> 4;
    const int wr = wave >> 1, wc = wave & 1;     // (BM/64) x 2 waves, 64x64 out
    const int bx = blockIdx.x, by = blockIdx.y;
    const int rowA0 = by * BM, rowB0 = bx * 128;

    f32x4 acc[4][4];
    const f32x4 zero = {0.f, 0.f, 0.f, 0.f};
#pragma unroll
    for (int i = 0; i < 4; ++i)
#pragma unroll
        for (int j = 0; j < 4; ++j) acc[i][j] = zero;

    // stage panel pnl (32 cols at col = pnl*32) into slot: linear LDS dest,
    // source chunk pre-swizzled by s(row) = (row>>1)&3 (== (idx>>3)&3).
    auto STAGE = [&](int slot, int pnl) {
        const int colbase = pnl * 32;
#pragma unroll
        for (int l = 0; l < LA; ++l) {
            const int base = l * TPB + wave * 64;   // wave-uniform
            const int idx = base + lane;
            const int row = idx >> 2;
            const int sch = ((idx & 3) ^ ((idx >> 3) & 3)) * 8;
            gload16(&A[(size_t)(rowA0 + row) * 1024 + colbase + sch],
                    &As[slot][base * 8]);
        }
#pragma unroll
        for (int l = 0; l < LB; ++l) {
            const int base = l * TPB + wave * 64;
            const int idx = base + lane;
            const int row = idx >> 2;
            const int sch = ((idx & 3) ^ ((idx >> 3) & 3)) * 8;
            gload16(&Bw[(size_t)(rowB0 + row) * 1024 + colbase + sch],
                    &Bs[slot][base * 8]);
        }
    };

    // prologue: panels 0,1; land own panel-0 loads; publish.
    STAGE(0, 0);
    STAGE(1, 1);
    if constexpr (L == 3) { asm volatile("s_waitcnt vmcnt(3)" ::: "memory"); }
    else                  { asm volatile("s_waitcnt vmcnt(4)" ::: "memory"); }
    __builtin_amdgcn_s_barrier();

    for (int p = 0; p < NP_; ++p) {
        const int slot = p % 3;
        bf16x8 a[4], b[4];
#pragma unroll
        for (int i = 0; i < 4; ++i) {
            const int row = wr * 64 + i * 16 + ml;
            a[i] = *(const bf16x8*)(&As[slot][row * 32 + ((quad ^ ((row >> 1) & 3)) << 3)]);
        }
#pragma unroll
        for (int j = 0; j < 4; ++j) {
            const int row = wc * 64 + j * 16 + ml;
            b[j] = *(const bf16x8*)(&Bs[slot][row * 32 + ((quad ^ ((row >> 1) & 3)) << 3)]);
        }
        if (p + 2 < NP_) STAGE((p + 2) % 3, p + 2);   // slot freed at phase p-1
        __builtin_amdgcn_s_barrier();
        asm volatile("s_waitcnt lgkmcnt(0)" ::: "memory");
        __builtin_amdgcn_sched_barrier(0);
        __builtin_amdgcn_s_setprio(1);
#pragma unroll
        for (int i = 0; i < 4; ++i)
#pragma unroll
            for (int j = 0; j < 4; ++j)
                acc[i][j] = __builtin_amdgcn_mfma_f32_16x16x32_bf16(a[i], b[j], acc[i][j], 0, 0, 0);
        __builtin_amdgcn_s_setprio(0);
        // end-of-phase counted wait: panel p+1 fully landed (own loads);
        // panel p+2's L loads stay in flight across the publishing barrier.
        if (p + 2 < NP_) {
            if constexpr (L == 3) { asm volatile("s_waitcnt vmcnt(3)" ::: "memory"); }
            else                  { asm volatile("s_waitcnt vmcnt(4)" ::: "memory"); }
        } else {
            asm volatile("s_waitcnt vmcnt(0)" ::: "memory");
        }
        __builtin_amdgcn_s_barrier();
    }

    // epilogue
    if constexpr (EPI == 2) {
        float* C = (float*)Cout;
#pragma unroll
        for (int i = 0; i < 4; ++i)
#pragma unroll
            for (int j = 0; j < 4; ++j)
#pragma unroll
                for (int r = 0; r < 4; ++r) {
                    int row = rowA0 + wr * 64 + i * 16 + quad * 4 + r;
                    int col = rowB0 + wc * 64 + j * 16 + ml;
                    C[(size_t)row * Ndim + col] = acc[i][j][r];
                }
    } else {
        if (bx < 16) {   // qk region, bf16
            u16* C = (u16*)Cout;
#pragma unroll
            for (int i = 0; i < 4; ++i)
#pragma unroll
                for (int j = 0; j < 4; ++j)
#pragma unroll
                    for (int r = 0; r < 4; ++r) {
                        int row = rowA0 + wr * 64 + i * 16 + quad * 4 + r;
                        int col = rowB0 + wc * 64 + j * 16 + ml;
                        C[(size_t)row * Ndim + col] = f2bf_hw(acc[i][j][r]);
                    }
        } else {         // V region -> transposed Vt
            u16* Vt = (u16*)C2;
#pragma unroll
            for (int i = 0; i < 4; ++i)
#pragma unroll
                for (int j = 0; j < 4; ++j) {
                    int row0 = rowA0 + wr * 64 + i * 16 + quad * 4;  // token, mult of 4
                    int col = rowB0 + wc * 64 + j * 16 + ml - 2048;  // V feature
                    int b = row0 >> 11;
                    int s0 = row0 & (S_ - 1);
                    union { u16 h[4]; ushort4 v; } pk;
#pragma unroll
                    for (int r = 0; r < 4; ++r) pk.h[r] = f2bf_hw(acc[i][j][r]);
                    *(ushort4*)(&Vt[((size_t)(b * D_ + col)) * S_ + s0]) = pk.v;
                }
        }
    }
}

// attn3: flash attention, swapped-QK^T, PV one-tile software lag. (unchanged)
__global__ __launch_bounds__(256, 3) void attn3(const u16* __restrict__ qk,
                                                const u16* __restrict__ Vt,
                                                u16* __restrict__ AO) {
    __shared__ u16 Klds[2][64 * 64];   // linear rows; chunk XOR-swizzled by row&7
    __shared__ u16 Vlds[2][64 * 64];
    __shared__ u16 Pw[4][32 * 72];     // per-wave 32q x 64k bf16, stride 72
    const int t = threadIdx.x;
    const int wave = t >> 6, lane = t & 63;
    const int ml = lane & 15, quad = lane >> 4;
    const int mhx = (ml & 8) >> 1;     // bank-spreading XOR term

    const int jj = blockIdx.x >> 6;      // 0..15
    const int bh = blockIdx.x & 63;      // head id
    const int t4 = jj >> 2, r4 = jj & 3;
    const int j = (t4 < 2) ? (15 - 4 * t4 - r4) : (12 - 4 * t4 + r4);
    const int b = bh >> 4, h = bh & 15;
    const size_t rowbase = (size_t)b * S_;

    const int srow8 = lane >> 3;                   // 0..7
    const int schunk = ((lane & 7) ^ srow8) * 8;   // swizzled source chunk

    const int qj0 = j * 128 + wave * 32;           // this wave's 32 q-rows
    const int ktw = 2 * j + (wave >> 1);           // last k-tile this wave needs
    const int ktmax = 2 * j + 1;                   // last k-tile in block

    u16* pwb = &Pw[wave][0];

    bf16x8 qf[2][2];   // [mi][kc], pre-scaled by 0.125
#pragma unroll
    for (int mi = 0; mi < 2; ++mi)
#pragma unroll
        for (int kc = 0; kc < 2; ++kc) {
            bf16x8 q = *(const bf16x8*)(&qk[(rowbase + qj0 + mi * 16 + ml) * QK_ +
                                            h * HD_ + kc * 32 + quad * 8]);
#pragma unroll
            for (int e = 0; e < 8; ++e) {
                float f = (float)q[e] * 0.125f;
                q[e] = (__bf16)f;
            }
            qf[mi][kc] = q;
        }

    f32x4 o[2][4];
    float m[2], ls[2];
    const f32x4 zero = {0.f, 0.f, 0.f, 0.f};
#pragma unroll
    for (int mi = 0; mi < 2; ++mi) {
#pragma unroll
        for (int nd = 0; nd < 4; ++nd) o[mi][nd] = zero;
        m[mi] = MASKVAL; ls[mi] = 0.f;
    }

    bf16x8 vf[4][2];   // V-frags of the previous tile

    auto STAGE = [&](int buf, int kt) {
        const int kb = kt * 64;
#pragma unroll
        for (int p = 0; p < 2; ++p) {
            const int rbase = wave * 16 + p * 8;
            gload16(&qk[(rowbase + kb + rbase + srow8) * QK_ + D_ + h * HD_ + schunk],
                    &Klds[buf][rbase * 64]);
            gload16(&Vt[(size_t)(bh * HD_ + rbase + srow8) * S_ + kb + schunk],
                    &Vlds[buf][rbase * 64]);
        }
    };

    auto PV = [&]() {
        bf16x8 pf[2][2];
#pragma unroll
        for (int mi = 0; mi < 2; ++mi)
#pragma unroll
            for (int kc = 0; kc < 2; ++kc)
                pf[mi][kc] = *(const bf16x8*)(&pwb[(mi * 16 + ml) * 72 +
                                                   (((kc * 4 + quad) ^ mhx) << 3)]);
        __builtin_amdgcn_s_setprio(1);
#pragma unroll
        for (int mi = 0; mi < 2; ++mi)
#pragma unroll
            for (int nd = 0; nd < 4; ++nd)
#pragma unroll
                for (int kc = 0; kc < 2; ++kc)
                    o[mi][nd] = __builtin_amdgcn_mfma_f32_16x16x32_bf16(pf[mi][kc], vf[nd][kc],
                                                                        o[mi][nd], 0, 0, 0);
        __builtin_amdgcn_s_setprio(0);
    };

    STAGE(0, 0);

    for (int kt = 0; kt <= ktmax; ++kt) {
        const int cur = kt & 1;
        if (kt < ktmax) STAGE(cur ^ 1, kt + 1);

        if (kt >= 1 && kt - 1 <= ktw) PV();

        if (kt < ktmax) {
            asm volatile("s_waitcnt vmcnt(4)" ::: "memory");
        } else {
            asm volatile("s_waitcnt vmcnt(0)" ::: "memory");
        }
        __builtin_amdgcn_s_barrier();

        if (kt <= ktw) {
            const int kb = kt * 64;
            f32x4 sc[2][4];
            __builtin_amdgcn_s_setprio(1);
#pragma unroll
            for (int ni = 0; ni < 4; ++ni) {
                const int row = ni * 16 + ml;
                bf16x8 kfa = *(const bf16x8*)(&Klds[cur][row * 64 + ((quad ^ (ml & 7)) << 3)]);
                bf16x8 kfb = *(const bf16x8*)(&Klds[cur][row * 64 + (((4 + quad) ^ (ml & 7)) << 3)]);
#pragma unroll
                for (int mi = 0; mi < 2; ++mi) {
                    f32x4 s = __builtin_amdgcn_mfma_f32_16x16x32_bf16(kfa, qf[mi][0], zero, 0, 0, 0);
                    sc[mi][ni] = __builtin_amdgcn_mfma_f32_16x16x32_bf16(kfb, qf[mi][1], s, 0, 0, 0);
                }
            }
            __builtin_amdgcn_s_setprio(0);

            if (kb + 63 > qj0) {
#pragma unroll
                for (int mi = 0; mi < 2; ++mi) {
                    const int q = qj0 + mi * 16 + ml;
#pragma unroll
                    for (int ni = 0; ni < 4; ++ni)
#pragma unroll
                        for (int r = 0; r < 4; ++r) {
                            int k = kb + ni * 16 + quad * 4 + r;
                            if (k > q) sc[mi][ni][r] = MASKVAL;
                        }
                }
            }

#pragma unroll
            for (int mi = 0; mi < 2; ++mi) {
                float tm = sc[mi][0][0];
#pragma unroll
                for (int ni = 0; ni < 4; ++ni)
#pragma unroll
                    for (int r = 0; r < 4; ++r) tm = fmaxf(tm, sc[mi][ni][r]);
                tm = fmaxf(tm, __shfl_xor(tm, 16, 64));
                tm = fmaxf(tm, __shfl_xor(tm, 32, 64));
                if (__any(tm > m[mi] + RESCALE_THR)) {
                    float mn = fmaxf(m[mi], tm);
                    float al = __expf(m[mi] - mn);
                    m[mi] = mn;
                    ls[mi] *= al;
                    float alr[4];
#pragma unroll
                    for (int r = 0; r < 4; ++r)
                        alr[r] = __shfl(al, (lane & 48) + ((lane & 48) >> 2) + r, 64);
#pragma unroll
                    for (int nd = 0; nd < 4; ++nd)
#pragma unroll
                        for (int r = 0; r < 4; ++r) o[mi][nd][r] *= alr[r];
                }
                float sum = 0.f;
#pragma unroll
                for (int ni = 0; ni < 4; ++ni)
#pragma unroll
                    for (int r = 0; r < 4; ++r) {
                        float e = __expf(sc[mi][ni][r] - m[mi]);
                        sc[mi][ni][r] = e;
                        sum += e;
                    }
                ls[mi] += sum;
#pragma unroll
                for (int ni = 0; ni < 4; ++ni) {
                    union { u16 h[4]; ushort4 v; } pk;
#pragma unroll
                    for (int r = 0; r < 4; ++r) pk.h[r] = f2bf_hw(sc[mi][ni][r]);
                    const int off = (mi * 16 + ml) * 72 +
                                    ((((2 * ni + (quad >> 1)) ^ mhx)) << 3) + ((quad & 1) << 2);
                    *(ushort4*)(&pwb[off]) = pk.v;
                }
            }
#pragma unroll
            for (int ni = 0; ni < 4; ++ni) {
                const int row = ni * 16 + ml;
#pragma unroll
                for (int kc = 0; kc < 2; ++kc)
                    vf[ni][kc] = *(const bf16x8*)(&Vlds[cur][row * 64 +
                                                            (((kc * 4 + quad) ^ (ml & 7)) << 3)]);
            }
        }
        asm volatile("s_waitcnt lgkmcnt(0)" ::: "memory");
        __builtin_amdgcn_s_barrier();
    }

    if (ktw == ktmax) PV();

#pragma unroll
    for (int mi = 0; mi < 2; ++mi) {
        float s = ls[mi];
        s += __shfl_xor(s, 16, 64);
        s += __shfl_xor(s, 32, 64);
        float rl = 1.0f / s;
        float rlr[4];
#pragma unroll
        for (int r = 0; r < 4; ++r)
            rlr[r] = __shfl(rl, (lane & 48) + ((lane & 48) >> 2) + r, 64);
#pragma unroll
        for (int nd = 0; nd < 4; ++nd)
#pragma unroll
            for (int r = 0; r < 4; ++r) {
                int srow = qj0 + mi * 16 + quad * 4 + r;
                AO[(rowbase + srow) * D_ + h * HD_ + nd * 16 + ml] =
                    f2bf_hw(o[mi][nd][r] * rlr[r]);
            }
    }
}

// 16B-per-thread d2d copy
__global__ __launch_bounds__(256) void copy16(const int4* __restrict__ src,
                                              int4* __restrict__ dst) {
    size_t i = (size_t)blockIdx.x * 256 + threadIdx.x;
    dst[i] = src[i];
}

extern "C" void kernel_launch(void* const* d_in, const int* in_sizes, int n_in,
                              void* d_out, int out_size, void* d_ws, size_t ws_size,
                              hipStream_t stream) {
    const float* x = (const float*)d_in[0];      // [B,S,D] f32
    const float* wqkv = (const float*)d_in[1];   // [3D,D] f32
    const float* wproj = (const float*)d_in[2];  // [D,D] f32
    float* out = (float*)d_out;                  // [B,S,D] fp32

    // workspace: qk [M,2D] bf16 (33.55 MB) + Vt [B*H*HD, S] bf16 (16.78 MB)
    u16* qkw = (u16*)d_ws;
    u16* Vtw = qkw + (size_t)M_ * QK_;

    // d_out doubles as bf16 scratch until the final projection:
    //   [0 , 8M)  xb (x bf16, dead after qkv gemm)  [8M,9M) wprojb  [9M,12M) wqkvb
    u16* xb = (u16*)d_out;
    u16* wprojb = xb + (size_t)M_ * D_;
    u16* wqkvb = wprojb + (size_t)D_ * D_;

    // If workspace is big enough, AO + wproj live there: copy16 disappears.
    const size_t need = ((size_t)M_ * QK_ + 8388608 /*Vt*/ + (size_t)M_ * D_ /*AO*/ +
                         (size_t)D_ * D_ /*wproj*/) * sizeof(u16);
    const bool bigws = ws_size >= need;
    u16* AOb    = bigws ? (Vtw + (size_t)8388608) : xb;
    u16* wprojd = bigws ? (AOb + (size_t)M_ * D_) : wprojb;
    u16* AOp    = bigws ? AOb : qkw;                       // proj A operand
    u16* wprojp = bigws ? wprojd : qkw + (size_t)M_ * D_;  // proj B operand

    // f32 -> bf16 converts (one-time)
    cvt_bf16<<<dim3(M_ * D_ / 2048), 256, 0, stream>>>(x, xb);
    cvt_bf16<<<dim3(D_ * D_ / 2048), 256, 0, stream>>>(wproj, wprojd);
    cvt_bf16<<<dim3(3 * D_ * D_ / 2048), 256, 0, stream>>>(wqkv, wqkvb);

    // fused QKV projection: BM=256, 512 thr, 72 KB LDS -> 2 blocks/CU
    gemm8p<3, 256, 512><<<dim3(3 * D_ / 128, M_ / 256), 512, 0, stream>>>(
        xb, wqkvb, qkw, Vtw, QK_);
    // attention: 1024 blocks, one q-tile each
    attn3<<<dim3(1024), 256, 0, stream>>>(qkw, Vtw, AOb);
    if (!bigws) {
        // move AO + wprojb (contiguous 9M u16) out of d_out before proj writes it
        copy16<<<dim3((unsigned)(((size_t)M_ * D_ + (size_t)D_ * D_) * 2 / (256 * 16))),
                 256, 0, stream>>>((const int4*)AOb, (int4*)qkw);
    }
    // output projection: BM=128, 256 thr, 48 KB LDS, 512 blocks -> 2 blocks/CU
    gemm8p<2, 128, 256><<<dim3(D_ / 128, M_ / 128), 256, 0, stream>>>(
        AOp, wprojp, out, nullptr, D_);
}

// Round 8
// 244.267 us; speedup vs baseline: 1.5040x; 1.0026x over previous
//
#include <hip/hip_runtime.h>

typedef unsigned short u16;
typedef unsigned int u32;

#define B_ 4
#define S_ 2048
#define D_ 1024
#define H_ 16
#define HD_ 64
#define M_ (B_ * S_)    // 8192 rows
#define QK_ (2 * D_)    // 2048 (Q|K feature stride in qk ws)
#define NP_ 32          // panels: K=1024 / 32-col halves
#define LOG2E 1.442695041f

typedef __bf16 bf16x8 __attribute__((ext_vector_type(8)));
typedef float f32x4 __attribute__((ext_vector_type(4)));

#define MASKVAL (-1.0e30f)
#define RESCALE_THR 8.0f

// hardware RNE f32->bf16
static __device__ __forceinline__ u16 f2bf_hw(float f) {
    union { __bf16 b; u16 u; } v;
    v.b = (__bf16)f;
    return v.u;
}

// async global->LDS, 16B per lane. dst must be wave-uniform base; HW adds lane*16.
static __device__ __forceinline__ void gload16(const u16* g, u16* l) {
    __builtin_amdgcn_global_load_lds(
        (const __attribute__((address_space(1))) void*)g,
        (__attribute__((address_space(3))) void*)l, 16, 0, 0);
}

// ---------------- elementwise f32 -> bf16 converts ----------
static __device__ __forceinline__ void cvt_body(const float* __restrict__ src,
                                                u16* __restrict__ dst, size_t blk,
                                                int tid) {
    size_t i = (blk * 256 + tid) * 8;
    float4 a = *(const float4*)(src + i);
    float4 b = *(const float4*)(src + i + 4);
    union { u16 h[8]; int4 v; } pk;
    pk.h[0] = f2bf_hw(a.x); pk.h[1] = f2bf_hw(a.y);
    pk.h[2] = f2bf_hw(a.z); pk.h[3] = f2bf_hw(a.w);
    pk.h[4] = f2bf_hw(b.x); pk.h[5] = f2bf_hw(b.y);
    pk.h[6] = f2bf_hw(b.z); pk.h[7] = f2bf_hw(b.w);
    *(int4*)(dst + i) = pk.v;
}

// fused x + wqkv convert: blocks [0,4096) -> x, [4096,5632) -> wqkv
__global__ __launch_bounds__(256) void cvt_xw(const float* __restrict__ x,
                                              const float* __restrict__ wqkv,
                                              u16* __restrict__ xb,
                                              u16* __restrict__ wqkvb) {
    int bid = blockIdx.x;
    if (bid < 4096) cvt_body(x, xb, bid, threadIdx.x);
    else            cvt_body(wqkv, wqkvb, bid - 4096, threadIdx.x);
}

__global__ __launch_bounds__(256) void cvt_one(const float* __restrict__ src,
                                               u16* __restrict__ dst) {
    cvt_body(src, dst, blockIdx.x, threadIdx.x);
}

// ---------------- deep-pipelined bf16 GEMM, 3-slot circular col-half LDS ----
// C[M,N] = A[M,1024] * B[N,1024]^T (A row-stride strideA, B row-stride strideB).
// BM x 128 tile, 32-col half-panels. Phase p: ds_read slot p%3 | stage panel
// p+2 -> slot (p+2)%3 | lgkmcnt(0) | 16 MFMA | vmcnt(L) | barrier.
// Single barrier per phase: STAGE(p+2) targets the slot whose readers all
// drained (own lgkmcnt(0)) before barrier(p-1); vmcnt(L)+barrier publishes p+1.
// EPI: 2 = fp32 C; 3 = fused qkv (bx<16 -> bf16 qk; bx>=16 -> transposed Vt).
template <int EPI, int BM, int TPB>
__global__ __launch_bounds__(TPB, (TPB == 512) ? 4 : 2)
void gemm8p(const u16* __restrict__ A, const u16* __restrict__ Bw,
            void* __restrict__ Cout, void* __restrict__ C2,
            int Ndim, int strideA, int strideB) {
    __shared__ u16 As[3][BM * 32];
    __shared__ u16 Bs[3][128 * 32];
    constexpr int LA = (BM * 4) / TPB;   // lane-loads per thread, A panel
    constexpr int LB = 512 / TPB;        // B panel
    constexpr int L = LA + LB;           // loads per panel per wave-lane
    const int t = threadIdx.x;
    const int wave = t >> 6, lane = t & 63;
    const int ml = lane & 15, quad = lane >> 4;
    const int wr = wave >> 1, wc = wave & 1;     // (BM/64) x 2 waves, 64x64 out
    const int bx = blockIdx.x, by = blockIdx.y;
    const int rowA0 = by * BM, rowB0 = bx * 128;

    f32x4 acc[4][4];
    const f32x4 zero = {0.f, 0.f, 0.f, 0.f};
#pragma unroll
    for (int i = 0; i < 4; ++i)
#pragma unroll
        for (int j = 0; j < 4; ++j) acc[i][j] = zero;

    auto STAGE = [&](int slot, int pnl) {
        const int colbase = pnl * 32;
#pragma unroll
        for (int l = 0; l < LA; ++l) {
            const int base = l * TPB + wave * 64;   // wave-uniform
            const int idx = base + lane;
            const int row = idx >> 2;
            const int sch = ((idx & 3) ^ ((idx >> 3) & 3)) * 8;
            gload16(&A[(size_t)(rowA0 + row) * strideA + colbase + sch],
                    &As[slot][base * 8]);
        }
#pragma unroll
        for (int l = 0; l < LB; ++l) {
            const int base = l * TPB + wave * 64;
            const int idx = base + lane;
            const int row = idx >> 2;
            const int sch = ((idx & 3) ^ ((idx >> 3) & 3)) * 8;
            gload16(&Bw[(size_t)(rowB0 + row) * strideB + colbase + sch],
                    &Bs[slot][base * 8]);
        }
    };

    // prologue: panels 0,1; land panel 0; publish.
    STAGE(0, 0);
    STAGE(1, 1);
    if constexpr (L == 3) { asm volatile("s_waitcnt vmcnt(3)" ::: "memory"); }
    else                  { asm volatile("s_waitcnt vmcnt(4)" ::: "memory"); }
    __builtin_amdgcn_s_barrier();

    for (int p = 0; p < NP_; ++p) {
        const int slot = p % 3;
        bf16x8 a[4], b[4];
#pragma unroll
        for (int i = 0; i < 4; ++i) {
            const int row = wr * 64 + i * 16 + ml;
            a[i] = *(const bf16x8*)(&As[slot][row * 32 + ((quad ^ ((row >> 1) & 3)) << 3)]);
        }
#pragma unroll
        for (int j = 0; j < 4; ++j) {
            const int row = wc * 64 + j * 16 + ml;
            b[j] = *(const bf16x8*)(&Bs[slot][row * 32 + ((quad ^ ((row >> 1) & 3)) << 3)]);
        }
        if (p + 2 < NP_) STAGE((p + 2) % 3, p + 2);   // slot's readers drained at barrier(p-1)
        asm volatile("s_waitcnt lgkmcnt(0)" ::: "memory");
        __builtin_amdgcn_sched_barrier(0);
        __builtin_amdgcn_s_setprio(1);
#pragma unroll
        for (int i = 0; i < 4; ++i)
#pragma unroll
            for (int j = 0; j < 4; ++j)
                acc[i][j] = __builtin_amdgcn_mfma_f32_16x16x32_bf16(a[i], b[j], acc[i][j], 0, 0, 0);
        __builtin_amdgcn_s_setprio(0);
        // counted wait: panel p+1 fully landed; panel p+2 stays in flight.
        if (p + 2 < NP_) {
            if constexpr (L == 3) { asm volatile("s_waitcnt vmcnt(3)" ::: "memory"); }
            else                  { asm volatile("s_waitcnt vmcnt(4)" ::: "memory"); }
        } else {
            asm volatile("s_waitcnt vmcnt(0)" ::: "memory");
        }
        __builtin_amdgcn_s_barrier();   // publishes panel p+1; frees slot p%3
    }

    // epilogue
    if constexpr (EPI == 2) {
        float* C = (float*)Cout;
#pragma unroll
        for (int i = 0; i < 4; ++i)
#pragma unroll
            for (int j = 0; j < 4; ++j)
#pragma unroll
                for (int r = 0; r < 4; ++r) {
                    int row = rowA0 + wr * 64 + i * 16 + quad * 4 + r;
                    int col = rowB0 + wc * 64 + j * 16 + ml;
                    C[(size_t)row * Ndim + col] = acc[i][j][r];
                }
    } else {
        if (bx < 16) {   // qk region, bf16
            u16* C = (u16*)Cout;
#pragma unroll
            for (int i = 0; i < 4; ++i)
#pragma unroll
                for (int j = 0; j < 4; ++j)
#pragma unroll
                    for (int r = 0; r < 4; ++r) {
                        int row = rowA0 + wr * 64 + i * 16 + quad * 4 + r;
                        int col = rowB0 + wc * 64 + j * 16 + ml;
                        C[(size_t)row * Ndim + col] = f2bf_hw(acc[i][j][r]);
                    }
        } else {         // V region -> transposed Vt
            u16* Vt = (u16*)C2;
#pragma unroll
            for (int i = 0; i < 4; ++i)
#pragma unroll
                for (int j = 0; j < 4; ++j) {
                    int row0 = rowA0 + wr * 64 + i * 16 + quad * 4;  // token, mult of 4
                    int col = rowB0 + wc * 64 + j * 16 + ml - 2048;  // V feature
                    int b = row0 >> 11;
                    int s0 = row0 & (S_ - 1);
                    union { u16 h[4]; ushort4 v; } pk;
#pragma unroll
                    for (int r = 0; r < 4; ++r) pk.h[r] = f2bf_hw(acc[i][j][r]);
                    *(ushort4*)(&Vt[((size_t)(b * D_ + col)) * S_ + s0]) = pk.v;
                }
        }
    }
}

// attn3: flash attention, swapped-QK^T, PV one-tile software lag.
// AO is written IN-PLACE into the Q-half of qk (rows own-block-only; cols =
// own-head 64-slice; K reads live in cols >=1024 -> no cross-block hazard).
// exp2-folded softmax: P = exp2(fma(s, log2e, -m*log2e)).
__global__ __launch_bounds__(256, 3) void attn3(u16* __restrict__ qk,
                                                const u16* __restrict__ Vt) {
    __shared__ u16 Klds[2][64 * 64];   // linear rows; chunk XOR-swizzled by row&7
    __shared__ u16 Vlds[2][64 * 64];
    __shared__ u16 Pw[4][32 * 72];     // per-wave 32q x 64k bf16, stride 72
    const int t = threadIdx.x;
    const int wave = t >> 6, lane = t & 63;
    const int ml = lane & 15, quad = lane >> 4;
    const int mhx = (ml & 8) >> 1;     // bank-spreading XOR term

    const int jj = blockIdx.x >> 6;      // 0..15
    const int bh = blockIdx.x & 63;      // head id
    const int t4 = jj >> 2, r4 = jj & 3;
    const int j = (t4 < 2) ? (15 - 4 * t4 - r4) : (12 - 4 * t4 + r4);
    const int b = bh >> 4, h = bh & 15;
    const size_t rowbase = (size_t)b * S_;

    const int srow8 = lane >> 3;                   // 0..7
    const int schunk = ((lane & 7) ^ srow8) * 8;   // swizzled source chunk

    const int qj0 = j * 128 + wave * 32;           // this wave's 32 q-rows
    const int ktw = 2 * j + (wave >> 1);           // last k-tile this wave needs
    const int ktmax = 2 * j + 1;                   // last k-tile in block

    u16* pwb = &Pw[wave][0];

    bf16x8 qf[2][2];   // [mi][kc], pre-scaled by 0.125
#pragma unroll
    for (int mi = 0; mi < 2; ++mi)
#pragma unroll
        for (int kc = 0; kc < 2; ++kc) {
            bf16x8 q = *(const bf16x8*)(&qk[(rowbase + qj0 + mi * 16 + ml) * QK_ +
                                            h * HD_ + kc * 32 + quad * 8]);
#pragma unroll
            for (int e = 0; e < 8; ++e) {
                float f = (float)q[e] * 0.125f;
                q[e] = (__bf16)f;
            }
            qf[mi][kc] = q;
        }

    f32x4 o[2][4];
    float m[2], ls[2];
    const f32x4 zero = {0.f, 0.f, 0.f, 0.f};
#pragma unroll
    for (int mi = 0; mi < 2; ++mi) {
#pragma unroll
        for (int nd = 0; nd < 4; ++nd) o[mi][nd] = zero;
        m[mi] = MASKVAL; ls[mi] = 0.f;
    }

    bf16x8 vf[4][2];   // V-frags of the previous tile

    auto STAGE = [&](int buf, int kt) {
        const int kb = kt * 64;
#pragma unroll
        for (int p = 0; p < 2; ++p) {
            const int rbase = wave * 16 + p * 8;
            gload16(&qk[(rowbase + kb + rbase + srow8) * QK_ + D_ + h * HD_ + schunk],
                    &Klds[buf][rbase * 64]);
            gload16(&Vt[(size_t)(bh * HD_ + rbase + srow8) * S_ + kb + schunk],
                    &Vlds[buf][rbase * 64]);
        }
    };

    auto PV = [&]() {
        bf16x8 pf[2][2];
#pragma unroll
        for (int mi = 0; mi < 2; ++mi)
#pragma unroll
            for (int kc = 0; kc < 2; ++kc)
                pf[mi][kc] = *(const bf16x8*)(&pwb[(mi * 16 + ml) * 72 +
                                                   (((kc * 4 + quad) ^ mhx) << 3)]);
        __builtin_amdgcn_s_setprio(1);
#pragma unroll
        for (int mi = 0; mi < 2; ++mi)
#pragma unroll
            for (int nd = 0; nd < 4; ++nd)
#pragma unroll
                for (int kc = 0; kc < 2; ++kc)
                    o[mi][nd] = __builtin_amdgcn_mfma_f32_16x16x32_bf16(pf[mi][kc], vf[nd][kc],
                                                                        o[mi][nd], 0, 0, 0);
        __builtin_amdgcn_s_setprio(0);
    };

    STAGE(0, 0);

    for (int kt = 0; kt <= ktmax; ++kt) {
        const int cur = kt & 1;
        if (kt < ktmax) STAGE(cur ^ 1, kt + 1);

        if (kt >= 1 && kt - 1 <= ktw) PV();

        if (kt < ktmax) {
            asm volatile("s_waitcnt vmcnt(4)" ::: "memory");
        } else {
            asm volatile("s_waitcnt vmcnt(0)" ::: "memory");
        }
        __builtin_amdgcn_s_barrier();

        if (kt <= ktw) {
            const int kb = kt * 64;
            f32x4 sc[2][4];
            __builtin_amdgcn_s_setprio(1);
#pragma unroll
            for (int ni = 0; ni < 4; ++ni) {
                const int row = ni * 16 + ml;
                bf16x8 kfa = *(const bf16x8*)(&Klds[cur][row * 64 + ((quad ^ (ml & 7)) << 3)]);
                bf16x8 kfb = *(const bf16x8*)(&Klds[cur][row * 64 + (((4 + quad) ^ (ml & 7)) << 3)]);
#pragma unroll
                for (int mi = 0; mi < 2; ++mi) {
                    f32x4 s = __builtin_amdgcn_mfma_f32_16x16x32_bf16(kfa, qf[mi][0], zero, 0, 0, 0);
                    sc[mi][ni] = __builtin_amdgcn_mfma_f32_16x16x32_bf16(kfb, qf[mi][1], s, 0, 0, 0);
                }
            }
            __builtin_amdgcn_s_setprio(0);

            if (kb + 63 > qj0) {   // boundary tile: causal mask
#pragma unroll
                for (int mi = 0; mi < 2; ++mi) {
                    const int q = qj0 + mi * 16 + ml;
#pragma unroll
                    for (int ni = 0; ni < 4; ++ni)
#pragma unroll
                        for (int r = 0; r < 4; ++r) {
                            int k = kb + ni * 16 + quad * 4 + r;
                            if (k > q) sc[mi][ni][r] = MASKVAL;
                        }
                }
            }

#pragma unroll
            for (int mi = 0; mi < 2; ++mi) {
                float tm = sc[mi][0][0];
#pragma unroll
                for (int ni = 0; ni < 4; ++ni)
#pragma unroll
                    for (int r = 0; r < 4; ++r) tm = fmaxf(tm, sc[mi][ni][r]);
                tm = fmaxf(tm, __shfl_xor(tm, 16, 64));
                tm = fmaxf(tm, __shfl_xor(tm, 32, 64));
                if (__any(tm > m[mi] + RESCALE_THR)) {
                    float mn = fmaxf(m[mi], tm);
                    float al = __builtin_amdgcn_exp2f((m[mi] - mn) * LOG2E);
                    m[mi] = mn;
                    ls[mi] *= al;
                    float alr[4];
#pragma unroll
                    for (int r = 0; r < 4; ++r)
                        alr[r] = __shfl(al, (lane & 48) + ((lane & 48) >> 2) + r, 64);
#pragma unroll
                    for (int nd = 0; nd < 4; ++nd)
#pragma unroll
                        for (int r = 0; r < 4; ++r) o[mi][nd][r] *= alr[r];
                }
                // exp2-folded: e = 2^(s*log2e - m*log2e)
                const float mm = m[mi] * LOG2E;
                float sum = 0.f;
#pragma unroll
                for (int ni = 0; ni < 4; ++ni)
#pragma unroll
                    for (int r = 0; r < 4; ++r) {
                        float e = __builtin_amdgcn_exp2f(__builtin_fmaf(sc[mi][ni][r], LOG2E, -mm));
                        sc[mi][ni][r] = e;
                        sum += e;
                    }
                ls[mi] += sum;
#pragma unroll
                for (int ni = 0; ni < 4; ++ni) {
                    union { u16 h[4]; ushort4 v; } pk;
#pragma unroll
                    for (int r = 0; r < 4; ++r) pk.h[r] = f2bf_hw(sc[mi][ni][r]);
                    const int off = (mi * 16 + ml) * 72 +
                                    ((((2 * ni + (quad >> 1)) ^ mhx)) << 3) + ((quad & 1) << 2);
                    *(ushort4*)(&pwb[off]) = pk.v;
                }
            }
#pragma unroll
            for (int ni = 0; ni < 4; ++ni) {
                const int row = ni * 16 + ml;
#pragma unroll
                for (int kc = 0; kc < 2; ++kc)
                    vf[ni][kc] = *(const bf16x8*)(&Vlds[cur][row * 64 +
                                                            (((kc * 4 + quad) ^ (ml & 7)) << 3)]);
            }
        }
        asm volatile("s_waitcnt lgkmcnt(0)" ::: "memory");
        __builtin_amdgcn_s_barrier();
    }

    if (ktw == ktmax) PV();

    // epilogue: AO written in-place into qk's Q-half (own rows x own h-slice)
#pragma unroll
    for (int mi = 0; mi < 2; ++mi) {
        float s = ls[mi];
        s += __shfl_xor(s, 16, 64);
        s += __shfl_xor(s, 32, 64);
        float rl = 1.0f / s;
        float rlr[4];
#pragma unroll
        for (int r = 0; r < 4; ++r)
            rlr[r] = __shfl(rl, (lane & 48) + ((lane & 48) >> 2) + r, 64);
#pragma unroll
        for (int nd = 0; nd < 4; ++nd)
#pragma unroll
            for (int r = 0; r < 4; ++r) {
                int srow = qj0 + mi * 16 + quad * 4 + r;
                qk[(rowbase + srow) * QK_ + h * HD_ + nd * 16 + ml] =
                    f2bf_hw(o[mi][nd][r] * rlr[r]);
            }
    }
}

extern "C" void kernel_launch(void* const* d_in, const int* in_sizes, int n_in,
                              void* d_out, int out_size, void* d_ws, size_t ws_size,
                              hipStream_t stream) {
    const float* x = (const float*)d_in[0];      // [B,S,D] f32
    const float* wqkv = (const float*)d_in[1];   // [3D,D] f32
    const float* wproj = (const float*)d_in[2];  // [D,D] f32
    float* out = (float*)d_out;                  // [B,S,D] fp32

    // workspace: qk [M,2D] bf16 (33.55 MB) + Vt [B*H*HD, S] bf16 (16.78 MB)
    u16* qkw = (u16*)d_ws;
    u16* Vtw = qkw + (size_t)M_ * QK_;

    // d_out doubles as bf16 scratch until the final projection:
    //   [0 , 8M)  xb   (x bf16, dead after qkv gemm)   [8M,11M) wqkvb
    u16* xb = (u16*)d_out;
    u16* wqkvb = xb + (size_t)M_ * D_;

    // 1. fused f32->bf16 converts for x and wqkv (one dispatch)
    cvt_xw<<<dim3(4096 + 1536), 256, 0, stream>>>(x, wqkv, xb, wqkvb);

    // 2. fused QKV projection: BM=256, 512 thr, 72 KB LDS -> 2 blocks/CU
    gemm8p<3, 256, 512><<<dim3(3 * D_ / 128, M_ / 256), 512, 0, stream>>>(
        xb, wqkvb, qkw, Vtw, QK_, D_, D_);

    // 3. attention: AO written in-place into qk's Q-half
    attn3<<<dim3(1024), 256, 0, stream>>>(qkw, Vtw);

    // 4. wproj f32->bf16 into the (now dead) Vt region
    cvt_one<<<dim3(512), 256, 0, stream>>>(wproj, Vtw);

    // 5. output projection: A = qk Q-half (row stride 2048), B = wproj bf16
    gemm8p<2, 128, 256><<<dim3(D_ / 128, M_ / 128), 256, 0, stream>>>(
        qkw, Vtw, out, nullptr, D_, QK_, D_);
}

// Round 9
// 243.653 us; speedup vs baseline: 1.5078x; 1.0025x over previous
//
#include <hip/hip_runtime.h>

typedef unsigned short u16;
typedef unsigned int u32;

#define B_ 4
#define S_ 2048
#define D_ 1024
#define H_ 16
#define HD_ 64
#define M_ (B_ * S_)    // 8192 rows
#define QK_ (2 * D_)    // 2048 (Q|K feature stride in qk ws)
#define NP_ 32          // panels: K=1024 / 32-col halves
#define LOG2E 1.442695041f

typedef __bf16 bf16x8 __attribute__((ext_vector_type(8)));
typedef float f32x4 __attribute__((ext_vector_type(4)));

#define MASKVAL (-1.0e30f)
#define RESCALE_THR 8.0f

// hardware RNE f32->bf16
static __device__ __forceinline__ u16 f2bf_hw(float f) {
    union { __bf16 b; u16 u; } v;
    v.b = (__bf16)f;
    return v.u;
}

// async global->LDS, 16B per lane. dst must be wave-uniform base; HW adds lane*16.
static __device__ __forceinline__ void gload16(const u16* g, u16* l) {
    __builtin_amdgcn_global_load_lds(
        (const __attribute__((address_space(1))) void*)g,
        (__attribute__((address_space(3))) void*)l, 16, 0, 0);
}

// ---------------- elementwise f32 -> bf16 converts ----------
static __device__ __forceinline__ void cvt_body(const float* __restrict__ src,
                                                u16* __restrict__ dst, size_t blk,
                                                int tid) {
    size_t i = (blk * 256 + tid) * 8;
    float4 a = *(const float4*)(src + i);
    float4 b = *(const float4*)(src + i + 4);
    union { u16 h[8]; int4 v; } pk;
    pk.h[0] = f2bf_hw(a.x); pk.h[1] = f2bf_hw(a.y);
    pk.h[2] = f2bf_hw(a.z); pk.h[3] = f2bf_hw(a.w);
    pk.h[4] = f2bf_hw(b.x); pk.h[5] = f2bf_hw(b.y);
    pk.h[6] = f2bf_hw(b.z); pk.h[7] = f2bf_hw(b.w);
    *(int4*)(dst + i) = pk.v;
}

// fused x + wqkv convert: blocks [0,4096) -> x, [4096,5632) -> wqkv
__global__ __launch_bounds__(256) void cvt_xw(const float* __restrict__ x,
                                              const float* __restrict__ wqkv,
                                              u16* __restrict__ xb,
                                              u16* __restrict__ wqkvb) {
    int bid = blockIdx.x;
    if (bid < 4096) cvt_body(x, xb, bid, threadIdx.x);
    else            cvt_body(wqkv, wqkvb, bid - 4096, threadIdx.x);
}

__global__ __launch_bounds__(256) void cvt_one(const float* __restrict__ src,
                                               u16* __restrict__ dst) {
    cvt_body(src, dst, blockIdx.x, threadIdx.x);
}

// ---------------- 256x256 high-intensity QKV GEMM (m201-geometry) ----------
// C[M,3072] = A[M,1024] * B[3072,1024]^T.  8 waves as 2x4, per-wave 128x64
// (acc[8][4] = 128 VGPR).  3-slot circular 32-col panels, 96 KB LDS,
// 1 block/CU.  Per phase: 12 ds_read_b128 (b2,b3 pinned last) | STAGE p+2 |
// lgkmcnt(2) | 16 MFMA (j=0,1) | lgkmcnt(0) | 16 MFMA (j=2,3) | vmcnt(4) |
// barrier.  bx<8 -> bf16 qk; bx>=8 -> transposed Vt.
__global__ __launch_bounds__(512, 2)
void gemm256(const u16* __restrict__ A, const u16* __restrict__ Bw,
             u16* __restrict__ Cqk, u16* __restrict__ Vt) {
    __shared__ u16 As[3][256 * 32];
    __shared__ u16 Bs[3][256 * 32];
    const int t = threadIdx.x;
    const int wave = t >> 6, lane = t & 63;
    const int ml = lane & 15, quad = lane >> 4;
    const int wr = wave >> 2, wc = wave & 3;     // 2x4 waves, 128x64 out each
    const int bx = blockIdx.x, by = blockIdx.y;
    const int rowA0 = by * 256, rowB0 = bx * 256;

    f32x4 acc[8][4];
    const f32x4 zero = {0.f, 0.f, 0.f, 0.f};
#pragma unroll
    for (int i = 0; i < 8; ++i)
#pragma unroll
        for (int j = 0; j < 4; ++j) acc[i][j] = zero;

    // stage panel pnl (32 cols) into slot: 2 A-loads + 2 B-loads per thread.
    auto STAGE = [&](int slot, int pnl) {
        const int colbase = pnl * 32;
#pragma unroll
        for (int l = 0; l < 2; ++l) {
            const int base = l * 512 + wave * 64;   // wave-uniform
            const int idx = base + lane;
            const int row = idx >> 2;
            const int sch = ((idx & 3) ^ ((idx >> 3) & 3)) * 8;
            gload16(&A[(size_t)(rowA0 + row) * 1024 + colbase + sch],
                    &As[slot][base * 8]);
        }
#pragma unroll
        for (int l = 0; l < 2; ++l) {
            const int base = l * 512 + wave * 64;
            const int idx = base + lane;
            const int row = idx >> 2;
            const int sch = ((idx & 3) ^ ((idx >> 3) & 3)) * 8;
            gload16(&Bw[(size_t)(rowB0 + row) * 1024 + colbase + sch],
                    &Bs[slot][base * 8]);
        }
    };

    // prologue: panels 0,1 (8 loads/wave); land panel 0 (vmcnt 4); publish.
    STAGE(0, 0);
    STAGE(1, 1);
    asm volatile("s_waitcnt vmcnt(4)" ::: "memory");
    __builtin_amdgcn_s_barrier();

    for (int p = 0; p < NP_; ++p) {
        const int slot = p % 3;
        bf16x8 a[8], b[4];
#pragma unroll
        for (int i = 0; i < 8; ++i) {
            const int row = wr * 128 + i * 16 + ml;
            a[i] = *(const bf16x8*)(&As[slot][row * 32 + ((quad ^ ((row >> 1) & 3)) << 3)]);
        }
#pragma unroll
        for (int j = 0; j < 2; ++j) {
            const int row = wc * 64 + j * 16 + ml;
            b[j] = *(const bf16x8*)(&Bs[slot][row * 32 + ((quad ^ ((row >> 1) & 3)) << 3)]);
        }
        __builtin_amdgcn_sched_barrier(0);   // pin: a[0..7],b[0..1] issued first
#pragma unroll
        for (int j = 2; j < 4; ++j) {
            const int row = wc * 64 + j * 16 + ml;
            b[j] = *(const bf16x8*)(&Bs[slot][row * 32 + ((quad ^ ((row >> 1) & 3)) << 3)]);
        }
        __builtin_amdgcn_sched_barrier(0);   // pin: b[2],b[3] are the last 2 DS ops
        if (p + 2 < NP_) STAGE((p + 2) % 3, p + 2);
        // DS ops retire in order: <=2 outstanding => a[] and b[0..1] landed.
        asm volatile("s_waitcnt lgkmcnt(2)" ::: "memory");
        __builtin_amdgcn_sched_barrier(0);
        __builtin_amdgcn_s_setprio(1);
#pragma unroll
        for (int i = 0; i < 8; ++i)
#pragma unroll
            for (int j = 0; j < 2; ++j)
                acc[i][j] = __builtin_amdgcn_mfma_f32_16x16x32_bf16(a[i], b[j], acc[i][j], 0, 0, 0);
        __builtin_amdgcn_s_setprio(0);
        asm volatile("s_waitcnt lgkmcnt(0)" ::: "memory");
        __builtin_amdgcn_sched_barrier(0);
        __builtin_amdgcn_s_setprio(1);
#pragma unroll
        for (int i = 0; i < 8; ++i)
#pragma unroll
            for (int j = 2; j < 4; ++j)
                acc[i][j] = __builtin_amdgcn_mfma_f32_16x16x32_bf16(a[i], b[j], acc[i][j], 0, 0, 0);
        __builtin_amdgcn_s_setprio(0);
        // counted wait: panel p+1 fully landed; panel p+2's 4 loads in flight.
        if (p + 2 < NP_) { asm volatile("s_waitcnt vmcnt(4)" ::: "memory"); }
        else             { asm volatile("s_waitcnt vmcnt(0)" ::: "memory"); }
        __builtin_amdgcn_s_barrier();   // publishes p+1; frees slot p%3
    }

    // epilogue: bx<8 -> qk bf16 (Ndim 2048); bx>=8 -> transposed Vt
    if (bx < 8) {
        u16* C = Cqk;
#pragma unroll
        for (int i = 0; i < 8; ++i)
#pragma unroll
            for (int j = 0; j < 4; ++j)
#pragma unroll
                for (int r = 0; r < 4; ++r) {
                    int row = rowA0 + wr * 128 + i * 16 + quad * 4 + r;
                    int col = rowB0 + wc * 64 + j * 16 + ml;
                    C[(size_t)row * QK_ + col] = f2bf_hw(acc[i][j][r]);
                }
    } else {
#pragma unroll
        for (int i = 0; i < 8; ++i)
#pragma unroll
            for (int j = 0; j < 4; ++j) {
                int row0 = rowA0 + wr * 128 + i * 16 + quad * 4;  // token, mult of 4
                int col = rowB0 + wc * 64 + j * 16 + ml - 2048;   // V feature
                int b = row0 >> 11;
                int s0 = row0 & (S_ - 1);
                union { u16 h[4]; ushort4 v; } pk;
#pragma unroll
                for (int r = 0; r < 4; ++r) pk.h[r] = f2bf_hw(acc[i][j][r]);
                *(ushort4*)(&Vt[((size_t)(b * D_ + col)) * S_ + s0]) = pk.v;
            }
    }
}

// ---------------- deep-pipelined bf16 GEMM, 3-slot circular (proj) ---------
// (unchanged known-good 128-tile structure, 2 blocks/CU)
template <int EPI, int BM, int TPB>
__global__ __launch_bounds__(TPB, (TPB == 512) ? 4 : 2)
void gemm8p(const u16* __restrict__ A, const u16* __restrict__ Bw,
            void* __restrict__ Cout, void* __restrict__ C2,
            int Ndim, int strideA, int strideB) {
    __shared__ u16 As[3][BM * 32];
    __shared__ u16 Bs[3][128 * 32];
    constexpr int LA = (BM * 4) / TPB;
    constexpr int LB = 512 / TPB;
    constexpr int L = LA + LB;
    const int t = threadIdx.x;
    const int wave = t >> 6, lane = t & 63;
    const int ml = lane & 15, quad = lane >> 4;
    const int wr = wave >> 1, wc = wave & 1;
    const int bx = blockIdx.x, by = blockIdx.y;
    const int rowA0 = by * BM, rowB0 = bx * 128;

    f32x4 acc[4][4];
    const f32x4 zero = {0.f, 0.f, 0.f, 0.f};
#pragma unroll
    for (int i = 0; i < 4; ++i)
#pragma unroll
        for (int j = 0; j < 4; ++j) acc[i][j] = zero;

    auto STAGE = [&](int slot, int pnl) {
        const int colbase = pnl * 32;
#pragma unroll
        for (int l = 0; l < LA; ++l) {
            const int base = l * TPB + wave * 64;
            const int idx = base + lane;
            const int row = idx >> 2;
            const int sch = ((idx & 3) ^ ((idx >> 3) & 3)) * 8;
            gload16(&A[(size_t)(rowA0 + row) * strideA + colbase + sch],
                    &As[slot][base * 8]);
        }
#pragma unroll
        for (int l = 0; l < LB; ++l) {
            const int base = l * TPB + wave * 64;
            const int idx = base + lane;
            const int row = idx >> 2;
            const int sch = ((idx & 3) ^ ((idx >> 3) & 3)) * 8;
            gload16(&Bw[(size_t)(rowB0 + row) * strideB + colbase + sch],
                    &Bs[slot][base * 8]);
        }
    };

    STAGE(0, 0);
    STAGE(1, 1);
    if constexpr (L == 3) { asm volatile("s_waitcnt vmcnt(3)" ::: "memory"); }
    else                  { asm volatile("s_waitcnt vmcnt(4)" ::: "memory"); }
    __builtin_amdgcn_s_barrier();

    for (int p = 0; p < NP_; ++p) {
        const int slot = p % 3;
        bf16x8 a[4], b[4];
#pragma unroll
        for (int i = 0; i < 4; ++i) {
            const int row = wr * 64 + i * 16 + ml;
            a[i] = *(const bf16x8*)(&As[slot][row * 32 + ((quad ^ ((row >> 1) & 3)) << 3)]);
        }
#pragma unroll
        for (int j = 0; j < 4; ++j) {
            const int row = wc * 64 + j * 16 + ml;
            b[j] = *(const bf16x8*)(&Bs[slot][row * 32 + ((quad ^ ((row >> 1) & 3)) << 3)]);
        }
        if (p + 2 < NP_) STAGE((p + 2) % 3, p + 2);
        asm volatile("s_waitcnt lgkmcnt(0)" ::: "memory");
        __builtin_amdgcn_sched_barrier(0);
        __builtin_amdgcn_s_setprio(1);
#pragma unroll
        for (int i = 0; i < 4; ++i)
#pragma unroll
            for (int j = 0; j < 4; ++j)
                acc[i][j] = __builtin_amdgcn_mfma_f32_16x16x32_bf16(a[i], b[j], acc[i][j], 0, 0, 0);
        __builtin_amdgcn_s_setprio(0);
        if (p + 2 < NP_) {
            if constexpr (L == 3) { asm volatile("s_waitcnt vmcnt(3)" ::: "memory"); }
            else                  { asm volatile("s_waitcnt vmcnt(4)" ::: "memory"); }
        } else {
            asm volatile("s_waitcnt vmcnt(0)" ::: "memory");
        }
        __builtin_amdgcn_s_barrier();
    }

    if constexpr (EPI == 2) {
        float* C = (float*)Cout;
#pragma unroll
        for (int i = 0; i < 4; ++i)
#pragma unroll
            for (int j = 0; j < 4; ++j)
#pragma unroll
                for (int r = 0; r < 4; ++r) {
                    int row = rowA0 + wr * 64 + i * 16 + quad * 4 + r;
                    int col = rowB0 + wc * 64 + j * 16 + ml;
                    C[(size_t)row * Ndim + col] = acc[i][j][r];
                }
    } else {
        u16* C = (u16*)Cout;
#pragma unroll
        for (int i = 0; i < 4; ++i)
#pragma unroll
            for (int j = 0; j < 4; ++j)
#pragma unroll
                for (int r = 0; r < 4; ++r) {
                    int row = rowA0 + wr * 64 + i * 16 + quad * 4 + r;
                    int col = rowB0 + wc * 64 + j * 16 + ml;
                    C[(size_t)row * Ndim + col] = f2bf_hw(acc[i][j][r]);
                }
    }
}

// attn3: flash attention, swapped-QK^T, PV one-tile software lag. (unchanged)
__global__ __launch_bounds__(256, 3) void attn3(u16* __restrict__ qk,
                                                const u16* __restrict__ Vt) {
    __shared__ u16 Klds[2][64 * 64];
    __shared__ u16 Vlds[2][64 * 64];
    __shared__ u16 Pw[4][32 * 72];
    const int t = threadIdx.x;
    const int wave = t >> 6, lane = t & 63;
    const int ml = lane & 15, quad = lane >> 4;
    const int mhx = (ml & 8) >> 1;

    const int jj = blockIdx.x >> 6;
    const int bh = blockIdx.x & 63;
    const int t4 = jj >> 2, r4 = jj & 3;
    const int j = (t4 < 2) ? (15 - 4 * t4 - r4) : (12 - 4 * t4 + r4);
    const int b = bh >> 4, h = bh & 15;
    const size_t rowbase = (size_t)b * S_;

    const int srow8 = lane >> 3;
    const int schunk = ((lane & 7) ^ srow8) * 8;

    const int qj0 = j * 128 + wave * 32;
    const int ktw = 2 * j + (wave >> 1);
    const int ktmax = 2 * j + 1;

    u16* pwb = &Pw[wave][0];

    bf16x8 qf[2][2];
#pragma unroll
    for (int mi = 0; mi < 2; ++mi)
#pragma unroll
        for (int kc = 0; kc < 2; ++kc) {
            bf16x8 q = *(const bf16x8*)(&qk[(rowbase + qj0 + mi * 16 + ml) * QK_ +
                                            h * HD_ + kc * 32 + quad * 8]);
#pragma unroll
            for (int e = 0; e < 8; ++e) {
                float f = (float)q[e] * 0.125f;
                q[e] = (__bf16)f;
            }
            qf[mi][kc] = q;
        }

    f32x4 o[2][4];
    float m[2], ls[2];
    const f32x4 zero = {0.f, 0.f, 0.f, 0.f};
#pragma unroll
    for (int mi = 0; mi < 2; ++mi) {
#pragma unroll
        for (int nd = 0; nd < 4; ++nd) o[mi][nd] = zero;
        m[mi] = MASKVAL; ls[mi] = 0.f;
    }

    bf16x8 vf[4][2];

    auto STAGE = [&](int buf, int kt) {
        const int kb = kt * 64;
#pragma unroll
        for (int p = 0; p < 2; ++p) {
            const int rbase = wave * 16 + p * 8;
            gload16(&qk[(rowbase + kb + rbase + srow8) * QK_ + D_ + h * HD_ + schunk],
                    &Klds[buf][rbase * 64]);
            gload16(&Vt[(size_t)(bh * HD_ + rbase + srow8) * S_ + kb + schunk],
                    &Vlds[buf][rbase * 64]);
        }
    };

    auto PV = [&]() {
        bf16x8 pf[2][2];
#pragma unroll
        for (int mi = 0; mi < 2; ++mi)
#pragma unroll
            for (int kc = 0; kc < 2; ++kc)
                pf[mi][kc] = *(const bf16x8*)(&pwb[(mi * 16 + ml) * 72 +
                                                   (((kc * 4 + quad) ^ mhx) << 3)]);
        __builtin_amdgcn_s_setprio(1);
#pragma unroll
        for (int mi = 0; mi < 2; ++mi)
#pragma unroll
            for (int nd = 0; nd < 4; ++nd)
#pragma unroll
                for (int kc = 0; kc < 2; ++kc)
                    o[mi][nd] = __builtin_amdgcn_mfma_f32_16x16x32_bf16(pf[mi][kc], vf[nd][kc],
                                                                        o[mi][nd], 0, 0, 0);
        __builtin_amdgcn_s_setprio(0);
    };

    STAGE(0, 0);

    for (int kt = 0; kt <= ktmax; ++kt) {
        const int cur = kt & 1;
        if (kt < ktmax) STAGE(cur ^ 1, kt + 1);

        if (kt >= 1 && kt - 1 <= ktw) PV();

        if (kt < ktmax) {
            asm volatile("s_waitcnt vmcnt(4)" ::: "memory");
        } else {
            asm volatile("s_waitcnt vmcnt(0)" ::: "memory");
        }
        __builtin_amdgcn_s_barrier();

        if (kt <= ktw) {
            const int kb = kt * 64;
            f32x4 sc[2][4];
            __builtin_amdgcn_s_setprio(1);
#pragma unroll
            for (int ni = 0; ni < 4; ++ni) {
                const int row = ni * 16 + ml;
                bf16x8 kfa = *(const bf16x8*)(&Klds[cur][row * 64 + ((quad ^ (ml & 7)) << 3)]);
                bf16x8 kfb = *(const bf16x8*)(&Klds[cur][row * 64 + (((4 + quad) ^ (ml & 7)) << 3)]);
#pragma unroll
                for (int mi = 0; mi < 2; ++mi) {
                    f32x4 s = __builtin_amdgcn_mfma_f32_16x16x32_bf16(kfa, qf[mi][0], zero, 0, 0, 0);
                    sc[mi][ni] = __builtin_amdgcn_mfma_f32_16x16x32_bf16(kfb, qf[mi][1], s, 0, 0, 0);
                }
            }
            __builtin_amdgcn_s_setprio(0);

            if (kb + 63 > qj0) {
#pragma unroll
                for (int mi = 0; mi < 2; ++mi) {
                    const int q = qj0 + mi * 16 + ml;
#pragma unroll
                    for (int ni = 0; ni < 4; ++ni)
#pragma unroll
                        for (int r = 0; r < 4; ++r) {
                            int k = kb + ni * 16 + quad * 4 + r;
                            if (k > q) sc[mi][ni][r] = MASKVAL;
                        }
                }
            }

#pragma unroll
            for (int mi = 0; mi < 2; ++mi) {
                float tm = sc[mi][0][0];
#pragma unroll
                for (int ni = 0; ni < 4; ++ni)
#pragma unroll
                    for (int r = 0; r < 4; ++r) tm = fmaxf(tm, sc[mi][ni][r]);
                tm = fmaxf(tm, __shfl_xor(tm, 16, 64));
                tm = fmaxf(tm, __shfl_xor(tm, 32, 64));
                if (__any(tm > m[mi] + RESCALE_THR)) {
                    float mn = fmaxf(m[mi], tm);
                    float al = __builtin_amdgcn_exp2f((m[mi] - mn) * LOG2E);
                    m[mi] = mn;
                    ls[mi] *= al;
                    float alr[4];
#pragma unroll
                    for (int r = 0; r < 4; ++r)
                        alr[r] = __shfl(al, (lane & 48) + ((lane & 48) >> 2) + r, 64);
#pragma unroll
                    for (int nd = 0; nd < 4; ++nd)
#pragma unroll
                        for (int r = 0; r < 4; ++r) o[mi][nd][r] *= alr[r];
                }
                const float mm = m[mi] * LOG2E;
                float sum = 0.f;
#pragma unroll
                for (int ni = 0; ni < 4; ++ni)
#pragma unroll
                    for (int r = 0; r < 4; ++r) {
                        float e = __builtin_amdgcn_exp2f(__builtin_fmaf(sc[mi][ni][r], LOG2E, -mm));
                        sc[mi][ni][r] = e;
                        sum += e;
                    }
                ls[mi] += sum;
#pragma unroll
                for (int ni = 0; ni < 4; ++ni) {
                    union { u16 h[4]; ushort4 v; } pk;
#pragma unroll
                    for (int r = 0; r < 4; ++r) pk.h[r] = f2bf_hw(sc[mi][ni][r]);
                    const int off = (mi * 16 + ml) * 72 +
                                    ((((2 * ni + (quad >> 1)) ^ mhx)) << 3) + ((quad & 1) << 2);
                    *(ushort4*)(&pwb[off]) = pk.v;
                }
            }
#pragma unroll
            for (int ni = 0; ni < 4; ++ni) {
                const int row = ni * 16 + ml;
#pragma unroll
                for (int kc = 0; kc < 2; ++kc)
                    vf[ni][kc] = *(const bf16x8*)(&Vlds[cur][row * 64 +
                                                            (((kc * 4 + quad) ^ (ml & 7)) << 3)]);
            }
        }
        asm volatile("s_waitcnt lgkmcnt(0)" ::: "memory");
        __builtin_amdgcn_s_barrier();
    }

    if (ktw == ktmax) PV();

#pragma unroll
    for (int mi = 0; mi < 2; ++mi) {
        float s = ls[mi];
        s += __shfl_xor(s, 16, 64);
        s += __shfl_xor(s, 32, 64);
        float rl = 1.0f / s;
        float rlr[4];
#pragma unroll
        for (int r = 0; r < 4; ++r)
            rlr[r] = __shfl(rl, (lane & 48) + ((lane & 48) >> 2) + r, 64);
#pragma unroll
        for (int nd = 0; nd < 4; ++nd)
#pragma unroll
            for (int r = 0; r < 4; ++r) {
                int srow = qj0 + mi * 16 + quad * 4 + r;
                qk[(rowbase + srow) * QK_ + h * HD_ + nd * 16 + ml] =
                    f2bf_hw(o[mi][nd][r] * rlr[r]);
            }
    }
}

extern "C" void kernel_launch(void* const* d_in, const int* in_sizes, int n_in,
                              void* d_out, int out_size, void* d_ws, size_t ws_size,
                              hipStream_t stream) {
    const float* x = (const float*)d_in[0];      // [B,S,D] f32
    const float* wqkv = (const float*)d_in[1];   // [3D,D] f32
    const float* wproj = (const float*)d_in[2];  // [D,D] f32
    float* out = (float*)d_out;                  // [B,S,D] fp32

    // workspace: qk [M,2D] bf16 (33.55 MB) + Vt [B*H*HD, S] bf16 (16.78 MB)
    u16* qkw = (u16*)d_ws;
    u16* Vtw = qkw + (size_t)M_ * QK_;

    // d_out doubles as bf16 scratch until the final projection:
    //   [0 , 8M)  xb   (x bf16, dead after qkv gemm)   [8M,11M) wqkvb
    u16* xb = (u16*)d_out;
    u16* wqkvb = xb + (size_t)M_ * D_;

    // 1. fused f32->bf16 converts for x and wqkv (one dispatch)
    cvt_xw<<<dim3(4096 + 1536), 256, 0, stream>>>(x, wqkv, xb, wqkvb);

    // 2. fused QKV projection: 256x256 tile, 8 waves of 128x64, 96 KB LDS
    gemm256<<<dim3(3 * D_ / 256, M_ / 256), 512, 0, stream>>>(
        xb, wqkvb, qkw, Vtw);

    // 3. attention: AO written in-place into qk's Q-half
    attn3<<<dim3(1024), 256, 0, stream>>>(qkw, Vtw);

    // 4. wproj f32->bf16 into the (now dead) Vt region
    cvt_one<<<dim3(512), 256, 0, stream>>>(wproj, Vtw);

    // 5. output projection: A = qk Q-half (row stride 2048), B = wproj bf16
    gemm8p<2, 128, 256><<<dim3(D_ / 128, M_ / 128), 256, 0, stream>>>(
        qkw, Vtw, out, nullptr, D_, QK_, D_);
}